// Round 1
// baseline (787.177 us; speedup 1.0000x reference)
//
#include <hip/hip_runtime.h>

#define F_IN 11
#define LN_EPS 1e-5f

// ---------------- CSR build ----------------
__global__ void k_hist(const int* __restrict__ tgt, int* __restrict__ deg, int E) {
  int i = blockIdx.x * 256 + threadIdx.x;
  if (i < E) atomicAdd(&deg[tgt[i]], 1);
}

__global__ void k_scan1(const int* __restrict__ deg, int* __restrict__ offs,
                        int* __restrict__ partials, int n) {
  __shared__ int s[256];
  int t = threadIdx.x;
  int i = blockIdx.x * 256 + t;
  int v = (i < n) ? deg[i] : 0;
  s[t] = v;
  __syncthreads();
  for (int d = 1; d < 256; d <<= 1) {
    int add = (t >= d) ? s[t - d] : 0;
    __syncthreads();
    s[t] += add;
    __syncthreads();
  }
  if (i < n) offs[i] = s[t] - v;          // exclusive
  if (t == 255) partials[blockIdx.x] = s[255];
}

__global__ void k_scan2(int* __restrict__ partials, int nb) {
  __shared__ int s[512];
  int t = threadIdx.x;
  int v = (t < nb) ? partials[t] : 0;
  s[t] = v;
  __syncthreads();
  for (int d = 1; d < 512; d <<= 1) {
    int add = (t >= d) ? s[t - d] : 0;
    __syncthreads();
    s[t] += add;
    __syncthreads();
  }
  if (t < nb) partials[t] = s[t] - v;     // exclusive
}

__global__ void k_scan3(int* __restrict__ offs, const int* __restrict__ partials, int n) {
  int i = blockIdx.x * 256 + threadIdx.x;
  if (i < n) offs[i] += partials[blockIdx.x];
}

__global__ void k_scatter(const int* __restrict__ src, const int* __restrict__ tgt,
                          const int* __restrict__ offs, int* __restrict__ cur,
                          int* __restrict__ csr, int E) {
  int i = blockIdx.x * 256 + threadIdx.x;
  if (i < E) {
    int t = tgt[i];
    int p = atomicAdd(&cur[t], 1);
    csr[offs[t] + p] = src[i];
  }
}

// ---------------- layer 0: aggregate 11-dim input (mean) ----------------
__global__ void k_agg_in(const float* __restrict__ x, const int* __restrict__ csr,
                         const int* __restrict__ offs, const int* __restrict__ deg,
                         float* __restrict__ out, int n) {
  int t = threadIdx.x;
  int lane = t & 15;
  int node = blockIdx.x * 16 + (t >> 4);
  if (node >= n) return;
  int o = offs[node], d = deg[node];
  float sum = 0.f;
  for (int e = 0; e < d; ++e) {
    int s = csr[o + e];
    if (lane < F_IN) sum += x[(size_t)s * F_IN + lane];
  }
  float rd = (d > 0) ? 1.f / (float)d : 1.f;
  if (lane < F_IN) out[(size_t)node * F_IN + lane] = sum * rd;
}

// ---------------- layer 0 linear (11->128) + LN + ReLU ----------------
__global__ __launch_bounds__(256) void k_lin0(
    const float* __restrict__ xin, const float* __restrict__ W,
    const float* __restrict__ b, const float* __restrict__ g,
    const float* __restrict__ be, const int* __restrict__ deg,
    float* __restrict__ xout, int n) {
  __shared__ float Ws[128 * F_IN];
  __shared__ float bs[128], gs[128], bes[128];
  __shared__ float xs[8][F_IN + 1];
  int t = threadIdx.x;
  for (int i = t; i < 128 * F_IN; i += 256) Ws[i] = W[i];
  if (t < 128) { bs[t] = b[t]; gs[t] = g[t]; bes[t] = be[t]; }
  int jg = t & 31, ng = t >> 5;  // 8 nodes per iter, one per 32-lane group
  for (int base = blockIdx.x * 8; base < n; base += gridDim.x * 8) {
    __syncthreads();
    if (t < 8 * F_IN) {
      int r = t / F_IN, c = t % F_IN;
      xs[r][c] = xin[(size_t)(base + r) * F_IN + c];
    }
    __syncthreads();
    int node = base + ng;
    float bm = (deg[node] > 0) ? 1.f : 0.f;
    float acc[4];
#pragma unroll
    for (int i = 0; i < 4; i++) acc[i] = bm * bs[4 * jg + i];
#pragma unroll
    for (int k = 0; k < F_IN; k++) {
      float xv = xs[ng][k];
#pragma unroll
      for (int i = 0; i < 4; i++) acc[i] += xv * Ws[(4 * jg + i) * F_IN + k];
    }
    float s1 = acc[0] + acc[1] + acc[2] + acc[3];
    float s2 = acc[0]*acc[0] + acc[1]*acc[1] + acc[2]*acc[2] + acc[3]*acc[3];
#pragma unroll
    for (int m = 1; m < 32; m <<= 1) {
      s1 += __shfl_xor(s1, m, 64);
      s2 += __shfl_xor(s2, m, 64);
    }
    float mu = s1 * (1.f / 128.f);
    float var = s2 * (1.f / 128.f) - mu * mu;
    float rs = rsqrtf(var + LN_EPS);
    float4 o;
    float* op = &o.x;
#pragma unroll
    for (int i = 0; i < 4; i++) {
      float v = (acc[i] - mu) * rs * gs[4 * jg + i] + bes[4 * jg + i];
      op[i] = fmaxf(v, 0.f);
    }
    *(float4*)&xout[(size_t)node * 128 + 4 * jg] = o;
  }
}

// ---------------- aggregate 128-dim (mean), wave per node ----------------
__global__ __launch_bounds__(256) void k_agg128(
    const float* __restrict__ x, const int* __restrict__ csr,
    const int* __restrict__ offs, const int* __restrict__ deg,
    float* __restrict__ out, int n) {
  int t = threadIdx.x;
  int lane = t & 63;
  int node = blockIdx.x * 4 + (t >> 6);
  if (node >= n) return;
  int o = offs[node], d = deg[node];
  const float2* X = (const float2*)x;
  float sx = 0.f, sy = 0.f;
  for (int e = 0; e < d; ++e) {
    int s = csr[o + e];
    float2 v = X[(size_t)s * 64 + lane];
    sx += v.x; sy += v.y;
  }
  float rd = (d > 0) ? 1.f / (float)d : 1.f;
  float2* O = (float2*)out;
  O[(size_t)node * 64 + lane] = make_float2(sx * rd, sy * rd);
}

// ---------------- layer 1 linear (128->128) + LN + ReLU ----------------
__global__ __launch_bounds__(256) void k_lin1(
    const float* __restrict__ xin, const float* __restrict__ W,
    const float* __restrict__ b, const float* __restrict__ g,
    const float* __restrict__ be, const int* __restrict__ deg,
    float* __restrict__ xout, int n) {
  __shared__ float Wt[128 * 128];       // Wt[k][j] = W[j][k]
  __shared__ float xs[16][130];
  __shared__ float bs[128], gs[128], bes[128];
  int t = threadIdx.x;
  for (int idx = t; idx < 16384; idx += 256) {
    int j = idx >> 7, k = idx & 127;
    Wt[k * 128 + j] = W[idx];
  }
  if (t < 128) { bs[t] = b[t]; gs[t] = g[t]; bes[t] = be[t]; }
  int jg = t & 31, ng = t >> 5;  // ng 0..7 -> node pair; 16 nodes/iter
  for (int base = blockIdx.x * 16; base < n; base += gridDim.x * 16) {
    __syncthreads();
#pragma unroll
    for (int i = 0; i < 8; i++) {
      int idx = t + 256 * i;           // 0..2047
      int r = idx >> 7, c = idx & 127;
      xs[r][c] = xin[(size_t)(base + r) * 128 + c];
    }
    __syncthreads();
    int nA = base + 2 * ng, nB = nA + 1;
    float bmA = (deg[nA] > 0) ? 1.f : 0.f;
    float bmB = (deg[nB] > 0) ? 1.f : 0.f;
    float accA[4], accB[4];
#pragma unroll
    for (int i = 0; i < 4; i++) { accA[i] = bmA * bs[4*jg+i]; accB[i] = bmB * bs[4*jg+i]; }
#pragma unroll 4
    for (int k = 0; k < 128; k++) {
      float xa = xs[2 * ng][k];
      float xb = xs[2 * ng + 1][k];
      float4 w = *(const float4*)&Wt[k * 128 + 4 * jg];
      accA[0] += xa * w.x; accA[1] += xa * w.y; accA[2] += xa * w.z; accA[3] += xa * w.w;
      accB[0] += xb * w.x; accB[1] += xb * w.y; accB[2] += xb * w.z; accB[3] += xb * w.w;
    }
    // LN + ReLU for both nodes (128 outputs live in this 32-lane group)
    float s1A = accA[0]+accA[1]+accA[2]+accA[3];
    float s2A = accA[0]*accA[0]+accA[1]*accA[1]+accA[2]*accA[2]+accA[3]*accA[3];
    float s1B = accB[0]+accB[1]+accB[2]+accB[3];
    float s2B = accB[0]*accB[0]+accB[1]*accB[1]+accB[2]*accB[2]+accB[3]*accB[3];
#pragma unroll
    for (int m = 1; m < 32; m <<= 1) {
      s1A += __shfl_xor(s1A, m, 64); s2A += __shfl_xor(s2A, m, 64);
      s1B += __shfl_xor(s1B, m, 64); s2B += __shfl_xor(s2B, m, 64);
    }
    float muA = s1A * (1.f/128.f), varA = s2A * (1.f/128.f) - muA*muA;
    float muB = s1B * (1.f/128.f), varB = s2B * (1.f/128.f) - muB*muB;
    float rsA = rsqrtf(varA + LN_EPS), rsB = rsqrtf(varB + LN_EPS);
    float4 oA, oB;
    float *pA = &oA.x, *pB = &oB.x;
#pragma unroll
    for (int i = 0; i < 4; i++) {
      float gv = gs[4*jg+i], bv = bes[4*jg+i];
      pA[i] = fmaxf((accA[i] - muA) * rsA * gv + bv, 0.f);
      pB[i] = fmaxf((accB[i] - muB) * rsB * gv + bv, 0.f);
    }
    *(float4*)&xout[(size_t)nA * 128 + 4 * jg] = oA;
    *(float4*)&xout[(size_t)nB * 128 + 4 * jg] = oB;
  }
}

// ---------------- layer 2 linear (128->64), bias, no LN ----------------
__global__ __launch_bounds__(256) void k_lin2(
    const float* __restrict__ xin, const float* __restrict__ W,
    const float* __restrict__ b, float* __restrict__ xout, int n) {
  __shared__ float Wt[128 * 64];        // Wt[k][j] = W[j][k]
  __shared__ float xs[32][130];
  __shared__ float bs[64];
  int t = threadIdx.x;
  for (int idx = t; idx < 8192; idx += 256) {
    int j = idx >> 7, k = idx & 127;
    Wt[k * 64 + j] = W[idx];
  }
  if (t < 64) bs[t] = b[t];
  int jg = t & 15, ng = t >> 4;  // ng 0..15 -> node pair; 32 nodes/iter
  for (int base = blockIdx.x * 32; base < n; base += gridDim.x * 32) {
    __syncthreads();
#pragma unroll
    for (int i = 0; i < 16; i++) {
      int idx = t + 256 * i;           // 0..4095
      int r = idx >> 7, c = idx & 127;
      xs[r][c] = xin[(size_t)(base + r) * 128 + c];
    }
    __syncthreads();
    int nA = base + 2 * ng, nB = nA + 1;
    float accA[4], accB[4];
#pragma unroll
    for (int i = 0; i < 4; i++) { accA[i] = bs[4*jg+i]; accB[i] = bs[4*jg+i]; }
#pragma unroll 4
    for (int k = 0; k < 128; k++) {
      float xa = xs[2 * ng][k];
      float xb = xs[2 * ng + 1][k];
      float4 w = *(const float4*)&Wt[k * 64 + 4 * jg];
      accA[0] += xa * w.x; accA[1] += xa * w.y; accA[2] += xa * w.z; accA[3] += xa * w.w;
      accB[0] += xb * w.x; accB[1] += xb * w.y; accB[2] += xb * w.z; accB[3] += xb * w.w;
    }
    *(float4*)&xout[(size_t)nA * 64 + 4 * jg] = *(float4*)accA;
    *(float4*)&xout[(size_t)nB * 64 + 4 * jg] = *(float4*)accB;
  }
}

// ---------------- aggregate 64-dim (mean) + final LN ----------------
__global__ __launch_bounds__(256) void k_agg64_ln(
    const float* __restrict__ x, const int* __restrict__ csr,
    const int* __restrict__ offs, const int* __restrict__ deg,
    const float* __restrict__ g, const float* __restrict__ be,
    float* __restrict__ out, int n) {
  int t = threadIdx.x;
  int lane = t & 63;
  int node = blockIdx.x * 4 + (t >> 6);
  if (node >= n) return;
  int o = offs[node], d = deg[node];
  float sum = 0.f;
  for (int e = 0; e < d; ++e) {
    int s = csr[o + e];
    sum += x[(size_t)s * 64 + lane];
  }
  float rd = (d > 0) ? 1.f / (float)d : 1.f;
  float v = sum * rd;
  float s1 = v, s2 = v * v;
#pragma unroll
  for (int m = 1; m < 64; m <<= 1) {
    s1 += __shfl_xor(s1, m, 64);
    s2 += __shfl_xor(s2, m, 64);
  }
  float mu = s1 * (1.f / 64.f);
  float var = s2 * (1.f / 64.f) - mu * mu;
  float rs = rsqrtf(var + LN_EPS);
  out[(size_t)node * 64 + lane] = (v - mu) * rs * g[lane] + be[lane];
}

extern "C" void kernel_launch(void* const* d_in, const int* in_sizes, int n_in,
                              void* d_out, int out_size, void* d_ws, size_t ws_size,
                              hipStream_t stream) {
  const float* nf  = (const float*)d_in[0];
  const int*   ei  = (const int*)d_in[1];
  const float* W0  = (const float*)d_in[2];
  const float* b0  = (const float*)d_in[3];
  const float* W1  = (const float*)d_in[4];
  const float* b1  = (const float*)d_in[5];
  const float* W2  = (const float*)d_in[6];
  const float* b2  = (const float*)d_in[7];
  const float* g0  = (const float*)d_in[8];
  const float* be0 = (const float*)d_in[9];
  const float* g1  = (const float*)d_in[10];
  const float* be1 = (const float*)d_in[11];
  const float* g2  = (const float*)d_in[12];
  const float* be2 = (const float*)d_in[13];
  float* out = (float*)d_out;

  int N = in_sizes[0] / F_IN;   // 100000
  int E = in_sizes[1] / 2;      // 1600000
  const int* src = ei;
  const int* tgt = ei + E;

  char* w = (char*)d_ws;
  auto al = [](size_t x) { return (x + 255) & ~(size_t)255; };
  int* deg      = (int*)w;  w += al((size_t)N * 4);
  int* offs     = (int*)w;  w += al((size_t)N * 4);
  int* cur      = (int*)w;  w += al((size_t)N * 4);
  int* partials = (int*)w;  w += al(4096);
  int* csr      = (int*)w;  w += al((size_t)E * 4);
  float* bufA   = (float*)w; w += al((size_t)N * 128 * 4);
  float* bufB   = (float*)w; w += al((size_t)N * 128 * 4);
  float* agg0   = (float*)w; w += al((size_t)N * F_IN * 4);

  hipMemsetAsync(deg, 0, (size_t)N * 4, stream);
  hipMemsetAsync(cur, 0, (size_t)N * 4, stream);

  int nb1 = (N + 255) / 256;   // 391
  k_hist<<<(E + 255) / 256, 256, 0, stream>>>(tgt, deg, E);
  k_scan1<<<nb1, 256, 0, stream>>>(deg, offs, partials, N);
  k_scan2<<<1, 512, 0, stream>>>(partials, nb1);
  k_scan3<<<nb1, 256, 0, stream>>>(offs, partials, N);
  k_scatter<<<(E + 255) / 256, 256, 0, stream>>>(src, tgt, offs, cur, csr, E);

  // layer 0: aggregate-first (11-dim), then linear+LN+ReLU
  k_agg_in<<<(N + 15) / 16, 256, 0, stream>>>(nf, csr, offs, deg, agg0, N);
  k_lin0<<<1024, 256, 0, stream>>>(agg0, W0, b0, g0, be0, deg, bufA, N);

  // layer 1: aggregate-first (128-dim), then linear+LN+ReLU
  k_agg128<<<(N + 3) / 4, 256, 0, stream>>>(bufA, csr, offs, deg, bufB, N);
  k_lin1<<<512, 256, 0, stream>>>(bufB, W1, b1, g1, be1, deg, bufA, N);

  // layer 2: transform-first (gather 64-dim), aggregate + final LN
  k_lin2<<<768, 256, 0, stream>>>(bufA, W2, b2, bufB, N);
  k_agg64_ln<<<(N + 3) / 4, 256, 0, stream>>>(bufB, csr, offs, deg, g2, be2, out, N);
}

// Round 2
// 589.739 us; speedup vs baseline: 1.3348x; 1.3348x over previous
//
#include <hip/hip_runtime.h>

#define F_IN 11
#define LN_EPS 1e-5f

__device__ inline unsigned short f2bf(float f) {
  unsigned int u = __float_as_uint(f);
  unsigned int r = u + 0x7fffu + ((u >> 16) & 1u);
  return (unsigned short)(r >> 16);
}
__device__ inline float bf_lo(unsigned v) { return __uint_as_float(v << 16); }
__device__ inline float bf_hi(unsigned v) { return __uint_as_float(v & 0xffff0000u); }

// ---------------- CSR build ----------------
__global__ void k_hist(const int* __restrict__ tgt, int* __restrict__ deg, int E) {
  int i = blockIdx.x * 256 + threadIdx.x;
  if (i < E) atomicAdd(&deg[tgt[i]], 1);
}

__global__ void k_scan1(const int* __restrict__ deg, int* __restrict__ offs,
                        int* __restrict__ partials, int n) {
  __shared__ int s[256];
  int t = threadIdx.x;
  int i = blockIdx.x * 256 + t;
  int v = (i < n) ? deg[i] : 0;
  s[t] = v;
  __syncthreads();
  for (int d = 1; d < 256; d <<= 1) {
    int add = (t >= d) ? s[t - d] : 0;
    __syncthreads();
    s[t] += add;
    __syncthreads();
  }
  if (i < n) offs[i] = s[t] - v;          // exclusive
  if (t == 255) partials[blockIdx.x] = s[255];
}

__global__ void k_scan2(int* __restrict__ partials, int nb) {
  __shared__ int s[512];
  int t = threadIdx.x;
  int v = (t < nb) ? partials[t] : 0;
  s[t] = v;
  __syncthreads();
  for (int d = 1; d < 512; d <<= 1) {
    int add = (t >= d) ? s[t - d] : 0;
    __syncthreads();
    s[t] += add;
    __syncthreads();
  }
  if (t < nb) partials[t] = s[t] - v;     // exclusive
}

__global__ void k_scan3(int* __restrict__ offs, const int* __restrict__ partials, int n) {
  int i = blockIdx.x * 256 + threadIdx.x;
  if (i < n) offs[i] += partials[blockIdx.x];
}

__global__ void k_scatter(const int* __restrict__ src, const int* __restrict__ tgt,
                          const int* __restrict__ offs, int* __restrict__ cur,
                          int* __restrict__ csr, int E) {
  int i = blockIdx.x * 256 + threadIdx.x;
  if (i < E) {
    int t = tgt[i];
    int p = atomicAdd(&cur[t], 1);
    csr[offs[t] + p] = src[i];
  }
}

// ---------------- layer 0: aggregate 11-dim input (mean), fp32 ----------------
__global__ void k_agg_in(const float* __restrict__ x, const int* __restrict__ csr,
                         const int* __restrict__ offs, const int* __restrict__ deg,
                         float* __restrict__ out, int n) {
  int t = threadIdx.x;
  int lane = t & 15;
  int node = blockIdx.x * 16 + (t >> 4);
  if (node >= n) return;
  int o = offs[node], d = deg[node];
  float sum = 0.f;
  int e = 0;
  for (; e + 4 <= d; e += 4) {
    int s0 = csr[o + e], s1 = csr[o + e + 1], s2 = csr[o + e + 2], s3 = csr[o + e + 3];
    float v0 = 0.f, v1 = 0.f, v2 = 0.f, v3 = 0.f;
    if (lane < F_IN) {
      v0 = x[(size_t)s0 * F_IN + lane];
      v1 = x[(size_t)s1 * F_IN + lane];
      v2 = x[(size_t)s2 * F_IN + lane];
      v3 = x[(size_t)s3 * F_IN + lane];
    }
    sum += (v0 + v1) + (v2 + v3);
  }
  for (; e < d; ++e) {
    int s = csr[o + e];
    if (lane < F_IN) sum += x[(size_t)s * F_IN + lane];
  }
  float rd = (d > 0) ? 1.f / (float)d : 1.f;
  if (lane < F_IN) out[(size_t)node * F_IN + lane] = sum * rd;
}

// ---------------- layer 0 linear (11->128) + LN + ReLU -> bf16 x1 ----------------
__global__ __launch_bounds__(256) void k_lin0(
    const float* __restrict__ xin, const float* __restrict__ W,
    const float* __restrict__ b, const float* __restrict__ g,
    const float* __restrict__ be, const int* __restrict__ deg,
    unsigned* __restrict__ xout, int n) {     // xout: bf16 packed, 64 uints/row
  __shared__ float Ws[128 * F_IN];
  __shared__ float bs[128], gs[128], bes[128];
  __shared__ float xs[8][F_IN + 1];
  int t = threadIdx.x;
  for (int i = t; i < 128 * F_IN; i += 256) Ws[i] = W[i];
  if (t < 128) { bs[t] = b[t]; gs[t] = g[t]; bes[t] = be[t]; }
  int jg = t & 31, ng = t >> 5;  // 8 nodes per iter, one per 32-lane group
  for (int base = blockIdx.x * 8; base < n; base += gridDim.x * 8) {
    __syncthreads();
    if (t < 8 * F_IN) {
      int r = t / F_IN, c = t % F_IN;
      xs[r][c] = xin[(size_t)(base + r) * F_IN + c];
    }
    __syncthreads();
    int node = base + ng;
    float bm = (deg[node] > 0) ? 1.f : 0.f;
    float acc[4];
#pragma unroll
    for (int i = 0; i < 4; i++) acc[i] = bm * bs[4 * jg + i];
#pragma unroll
    for (int k = 0; k < F_IN; k++) {
      float xv = xs[ng][k];
#pragma unroll
      for (int i = 0; i < 4; i++) acc[i] += xv * Ws[(4 * jg + i) * F_IN + k];
    }
    float s1 = acc[0] + acc[1] + acc[2] + acc[3];
    float s2 = acc[0]*acc[0] + acc[1]*acc[1] + acc[2]*acc[2] + acc[3]*acc[3];
#pragma unroll
    for (int m = 1; m < 32; m <<= 1) {
      s1 += __shfl_xor(s1, m, 64);
      s2 += __shfl_xor(s2, m, 64);
    }
    float mu = s1 * (1.f / 128.f);
    float var = s2 * (1.f / 128.f) - mu * mu;
    float rs = rsqrtf(var + LN_EPS);
    float o[4];
#pragma unroll
    for (int i = 0; i < 4; i++)
      o[i] = fmaxf((acc[i] - mu) * rs * gs[4 * jg + i] + bes[4 * jg + i], 0.f);
    uint2 pk;
    pk.x = (unsigned)f2bf(o[0]) | ((unsigned)f2bf(o[1]) << 16);
    pk.y = (unsigned)f2bf(o[2]) | ((unsigned)f2bf(o[3]) << 16);
    ((uint2*)xout)[(size_t)node * 32 + jg] = pk;   // byte: node*256 + jg*8
  }
}

// ---------------- aggregate 128-dim bf16 (mean) -> fp32, wave per node ----------------
__global__ __launch_bounds__(256) void k_agg128(
    const unsigned* __restrict__ X, const int* __restrict__ csr,
    const int* __restrict__ offs, const int* __restrict__ deg,
    float* __restrict__ out, int n) {
  int t = threadIdx.x;
  int lane = t & 63;
  int node = blockIdx.x * 4 + (t >> 6);
  if (node >= n) return;
  int o = offs[node], d = deg[node];
  float sx = 0.f, sy = 0.f;
  int e = 0;
  for (; e + 4 <= d; e += 4) {
    int s0 = csr[o + e], s1 = csr[o + e + 1], s2 = csr[o + e + 2], s3 = csr[o + e + 3];
    unsigned v0 = X[(size_t)s0 * 64 + lane];
    unsigned v1 = X[(size_t)s1 * 64 + lane];
    unsigned v2 = X[(size_t)s2 * 64 + lane];
    unsigned v3 = X[(size_t)s3 * 64 + lane];
    sx += (bf_lo(v0) + bf_lo(v1)) + (bf_lo(v2) + bf_lo(v3));
    sy += (bf_hi(v0) + bf_hi(v1)) + (bf_hi(v2) + bf_hi(v3));
  }
  for (; e < d; ++e) {
    unsigned v = X[(size_t)csr[o + e] * 64 + lane];
    sx += bf_lo(v);
    sy += bf_hi(v);
  }
  float rd = (d > 0) ? 1.f / (float)d : 1.f;
  ((float2*)out)[(size_t)node * 64 + lane] = make_float2(sx * rd, sy * rd);
}

// ---------------- layer 1 linear (128->128) + LN + ReLU, IN-PLACE fp32 ----------------
__global__ __launch_bounds__(256) void k_lin1(
    float* __restrict__ xio, const float* __restrict__ W,
    const float* __restrict__ b, const float* __restrict__ g,
    const float* __restrict__ be, const int* __restrict__ deg, int n) {
  __shared__ float Wt[128 * 128];       // Wt[k][j] = W[j][k]
  __shared__ float xs[16][130];
  __shared__ float bs[128], gs[128], bes[128];
  int t = threadIdx.x;
  for (int idx = t; idx < 16384; idx += 256) {
    int j = idx >> 7, k = idx & 127;
    Wt[k * 128 + j] = W[idx];
  }
  if (t < 128) { bs[t] = b[t]; gs[t] = g[t]; bes[t] = be[t]; }
  int jg = t & 31, ng = t >> 5;  // ng 0..7 -> node pair; 16 nodes/iter
  for (int base = blockIdx.x * 16; base < n; base += gridDim.x * 16) {
    __syncthreads();
#pragma unroll
    for (int i = 0; i < 8; i++) {
      int idx = t + 256 * i;           // 0..2047
      int r = idx >> 7, c = idx & 127;
      xs[r][c] = xio[(size_t)(base + r) * 128 + c];
    }
    __syncthreads();
    int nA = base + 2 * ng, nB = nA + 1;
    float bmA = (deg[nA] > 0) ? 1.f : 0.f;
    float bmB = (deg[nB] > 0) ? 1.f : 0.f;
    float accA[4], accB[4];
#pragma unroll
    for (int i = 0; i < 4; i++) { accA[i] = bmA * bs[4*jg+i]; accB[i] = bmB * bs[4*jg+i]; }
#pragma unroll 4
    for (int k = 0; k < 128; k++) {
      float xa = xs[2 * ng][k];
      float xb = xs[2 * ng + 1][k];
      float4 w = *(const float4*)&Wt[k * 128 + 4 * jg];
      accA[0] += xa * w.x; accA[1] += xa * w.y; accA[2] += xa * w.z; accA[3] += xa * w.w;
      accB[0] += xb * w.x; accB[1] += xb * w.y; accB[2] += xb * w.z; accB[3] += xb * w.w;
    }
    float s1A = accA[0]+accA[1]+accA[2]+accA[3];
    float s2A = accA[0]*accA[0]+accA[1]*accA[1]+accA[2]*accA[2]+accA[3]*accA[3];
    float s1B = accB[0]+accB[1]+accB[2]+accB[3];
    float s2B = accB[0]*accB[0]+accB[1]*accB[1]+accB[2]*accB[2]+accB[3]*accB[3];
#pragma unroll
    for (int m = 1; m < 32; m <<= 1) {
      s1A += __shfl_xor(s1A, m, 64); s2A += __shfl_xor(s2A, m, 64);
      s1B += __shfl_xor(s1B, m, 64); s2B += __shfl_xor(s2B, m, 64);
    }
    float muA = s1A * (1.f/128.f), varA = s2A * (1.f/128.f) - muA*muA;
    float muB = s1B * (1.f/128.f), varB = s2B * (1.f/128.f) - muB*muB;
    float rsA = rsqrtf(varA + LN_EPS), rsB = rsqrtf(varB + LN_EPS);
    float4 oA, oB;
    float *pA = &oA.x, *pB = &oB.x;
#pragma unroll
    for (int i = 0; i < 4; i++) {
      float gv = gs[4*jg+i], bv = bes[4*jg+i];
      pA[i] = fmaxf((accA[i] - muA) * rsA * gv + bv, 0.f);
      pB[i] = fmaxf((accB[i] - muB) * rsB * gv + bv, 0.f);
    }
    *(float4*)&xio[(size_t)nA * 128 + 4 * jg] = oA;
    *(float4*)&xio[(size_t)nB * 128 + 4 * jg] = oB;
  }
}

// ---------------- layer 2 linear (128->64) + bias -> bf16 xt2 ----------------
__global__ __launch_bounds__(256) void k_lin2(
    const float* __restrict__ xin, const float* __restrict__ W,
    const float* __restrict__ b, unsigned* __restrict__ xout, int n) {
  __shared__ float Wt[128 * 64];        // Wt[k][j] = W[j][k]
  __shared__ float xs[32][130];
  __shared__ float bs[64];
  int t = threadIdx.x;
  for (int idx = t; idx < 8192; idx += 256) {
    int j = idx >> 7, k = idx & 127;
    Wt[k * 64 + j] = W[idx];
  }
  if (t < 64) bs[t] = b[t];
  int jg = t & 15, ng = t >> 4;  // ng 0..15 -> node pair; 32 nodes/iter
  for (int base = blockIdx.x * 32; base < n; base += gridDim.x * 32) {
    __syncthreads();
#pragma unroll
    for (int i = 0; i < 16; i++) {
      int idx = t + 256 * i;           // 0..4095
      int r = idx >> 7, c = idx & 127;
      xs[r][c] = xin[(size_t)(base + r) * 128 + c];
    }
    __syncthreads();
    int nA = base + 2 * ng, nB = nA + 1;
    float accA[4], accB[4];
#pragma unroll
    for (int i = 0; i < 4; i++) { accA[i] = bs[4*jg+i]; accB[i] = bs[4*jg+i]; }
#pragma unroll 4
    for (int k = 0; k < 128; k++) {
      float xa = xs[2 * ng][k];
      float xb = xs[2 * ng + 1][k];
      float4 w = *(const float4*)&Wt[k * 64 + 4 * jg];
      accA[0] += xa * w.x; accA[1] += xa * w.y; accA[2] += xa * w.z; accA[3] += xa * w.w;
      accB[0] += xb * w.x; accB[1] += xb * w.y; accB[2] += xb * w.z; accB[3] += xb * w.w;
    }
    uint2 pkA, pkB;
    pkA.x = (unsigned)f2bf(accA[0]) | ((unsigned)f2bf(accA[1]) << 16);
    pkA.y = (unsigned)f2bf(accA[2]) | ((unsigned)f2bf(accA[3]) << 16);
    pkB.x = (unsigned)f2bf(accB[0]) | ((unsigned)f2bf(accB[1]) << 16);
    pkB.y = (unsigned)f2bf(accB[2]) | ((unsigned)f2bf(accB[3]) << 16);
    ((uint2*)xout)[(size_t)nA * 16 + jg] = pkA;   // byte: nA*128 + jg*8
    ((uint2*)xout)[(size_t)nB * 16 + jg] = pkB;
  }
}

// ---------------- aggregate 64-dim bf16 (mean) + final LN, half-wave/node ----------------
__global__ __launch_bounds__(256) void k_agg64_ln(
    const unsigned* __restrict__ X, const int* __restrict__ csr,
    const int* __restrict__ offs, const int* __restrict__ deg,
    const float* __restrict__ g, const float* __restrict__ be,
    float* __restrict__ out, int n) {
  int t = threadIdx.x;
  int lane = t & 31;
  int node = blockIdx.x * 8 + (t >> 5);
  if (node >= n) return;
  int o = offs[node], d = deg[node];
  float sx = 0.f, sy = 0.f;
  int e = 0;
  for (; e + 4 <= d; e += 4) {
    int s0 = csr[o + e], s1 = csr[o + e + 1], s2 = csr[o + e + 2], s3 = csr[o + e + 3];
    unsigned v0 = X[(size_t)s0 * 32 + lane];
    unsigned v1 = X[(size_t)s1 * 32 + lane];
    unsigned v2 = X[(size_t)s2 * 32 + lane];
    unsigned v3 = X[(size_t)s3 * 32 + lane];
    sx += (bf_lo(v0) + bf_lo(v1)) + (bf_lo(v2) + bf_lo(v3));
    sy += (bf_hi(v0) + bf_hi(v1)) + (bf_hi(v2) + bf_hi(v3));
  }
  for (; e < d; ++e) {
    unsigned v = X[(size_t)csr[o + e] * 32 + lane];
    sx += bf_lo(v);
    sy += bf_hi(v);
  }
  float rd = (d > 0) ? 1.f / (float)d : 1.f;
  float vx = sx * rd, vy = sy * rd;
  float s1 = vx + vy, s2 = vx * vx + vy * vy;
#pragma unroll
  for (int m = 1; m < 32; m <<= 1) {   // stays within the 32-lane half
    s1 += __shfl_xor(s1, m, 64);
    s2 += __shfl_xor(s2, m, 64);
  }
  float mu = s1 * (1.f / 64.f);
  float var = s2 * (1.f / 64.f) - mu * mu;
  float rs = rsqrtf(var + LN_EPS);
  float2 gb = ((const float2*)g)[lane];
  float2 bb = ((const float2*)be)[lane];
  float2 o2;
  o2.x = (vx - mu) * rs * gb.x + bb.x;
  o2.y = (vy - mu) * rs * gb.y + bb.y;
  ((float2*)out)[(size_t)node * 32 + lane] = o2;
}

extern "C" void kernel_launch(void* const* d_in, const int* in_sizes, int n_in,
                              void* d_out, int out_size, void* d_ws, size_t ws_size,
                              hipStream_t stream) {
  const float* nf  = (const float*)d_in[0];
  const int*   ei  = (const int*)d_in[1];
  const float* W0  = (const float*)d_in[2];
  const float* b0  = (const float*)d_in[3];
  const float* W1  = (const float*)d_in[4];
  const float* b1  = (const float*)d_in[5];
  const float* W2  = (const float*)d_in[6];
  const float* b2  = (const float*)d_in[7];
  const float* g0  = (const float*)d_in[8];
  const float* be0 = (const float*)d_in[9];
  const float* g1  = (const float*)d_in[10];
  const float* be1 = (const float*)d_in[11];
  const float* g2  = (const float*)d_in[12];
  const float* be2 = (const float*)d_in[13];
  float* out = (float*)d_out;

  int N = in_sizes[0] / F_IN;   // 100000
  int E = in_sizes[1] / 2;      // 1600000
  const int* src = ei;
  const int* tgt = ei + E;

  char* w = (char*)d_ws;
  auto al = [](size_t x) { return (x + 255) & ~(size_t)255; };
  int* deg      = (int*)w;  w += al((size_t)N * 4);
  int* offs     = (int*)w;  w += al((size_t)N * 4);
  int* cur      = (int*)w;  w += al((size_t)N * 4);
  int* partials = (int*)w;  w += al(4096);
  int* csr      = (int*)w;  w += al((size_t)E * 4);
  // R1: 51.2 MB — agg0 (fp32 N*11) lives here first, then aggB/lin1 in-place fp32 N*128
  float* R1     = (float*)w; w += al((size_t)N * 128 * 4);
  // R2: 25.6 MB — x1 bf16 (N*128), later xt2 bf16 (N*64)
  unsigned* R2  = (unsigned*)w; w += al((size_t)N * 64 * 4);
  float* agg0   = R1;

  hipMemsetAsync(deg, 0, (size_t)N * 4, stream);
  hipMemsetAsync(cur, 0, (size_t)N * 4, stream);

  int nb1 = (N + 255) / 256;   // 391
  k_hist<<<(E + 255) / 256, 256, 0, stream>>>(tgt, deg, E);
  k_scan1<<<nb1, 256, 0, stream>>>(deg, offs, partials, N);
  k_scan2<<<1, 512, 0, stream>>>(partials, nb1);
  k_scan3<<<nb1, 256, 0, stream>>>(offs, partials, N);
  k_scatter<<<(E + 255) / 256, 256, 0, stream>>>(src, tgt, offs, cur, csr, E);

  // layer 0: aggregate-first (11-dim fp32), linear+LN+ReLU -> bf16 x1 (R2)
  k_agg_in<<<(N + 15) / 16, 256, 0, stream>>>(nf, csr, offs, deg, agg0, N);
  k_lin0<<<1024, 256, 0, stream>>>(agg0, W0, b0, g0, be0, deg, R2, N);

  // layer 1: aggregate bf16 x1 -> fp32 (R1), linear+LN+ReLU in-place (R1)
  k_agg128<<<(N + 3) / 4, 256, 0, stream>>>(R2, csr, offs, deg, R1, N);
  k_lin1<<<512, 256, 0, stream>>>(R1, W1, b1, g1, be1, deg, N);

  // layer 2: linear -> bf16 xt2 (R2), aggregate + final LN -> out
  k_lin2<<<768, 256, 0, stream>>>(R1, W2, b2, R2, N);
  k_agg64_ln<<<(N + 7) / 8, 256, 0, stream>>>(R2, csr, offs, deg, g2, be2, out, N);
}

// Round 3
// 482.771 us; speedup vs baseline: 1.6305x; 1.2216x over previous
//
#include <hip/hip_runtime.h>

#define F_IN 11
#define LN_EPS 1e-5f

typedef __attribute__((ext_vector_type(8))) short short8;
typedef __attribute__((ext_vector_type(4))) float f32x4;

__device__ inline unsigned short f2bf(float f) {
  unsigned int u = __float_as_uint(f);
  unsigned int r = u + 0x7fffu + ((u >> 16) & 1u);
  return (unsigned short)(r >> 16);
}
__device__ inline float bf_lo(unsigned v) { return __uint_as_float(v << 16); }
__device__ inline float bf_hi(unsigned v) { return __uint_as_float(v & 0xffff0000u); }

// ---------------- CSR build ----------------
__global__ void k_hist(const int* __restrict__ tgt, int* __restrict__ deg, int E) {
  int i = blockIdx.x * 256 + threadIdx.x;
  if (i < E) atomicAdd(&deg[tgt[i]], 1);
}

__global__ void k_scan1(const int* __restrict__ deg, int* __restrict__ offs,
                        int* __restrict__ partials, int n) {
  __shared__ int s[256];
  int t = threadIdx.x;
  int i = blockIdx.x * 256 + t;
  int v = (i < n) ? deg[i] : 0;
  s[t] = v;
  __syncthreads();
  for (int d = 1; d < 256; d <<= 1) {
    int add = (t >= d) ? s[t - d] : 0;
    __syncthreads();
    s[t] += add;
    __syncthreads();
  }
  if (i < n) offs[i] = s[t] - v;          // exclusive
  if (t == 255) partials[blockIdx.x] = s[255];
}

__global__ void k_scan2(int* __restrict__ partials, int nb) {
  __shared__ int s[512];
  int t = threadIdx.x;
  int v = (t < nb) ? partials[t] : 0;
  s[t] = v;
  __syncthreads();
  for (int d = 1; d < 512; d <<= 1) {
    int add = (t >= d) ? s[t - d] : 0;
    __syncthreads();
    s[t] += add;
    __syncthreads();
  }
  if (t < nb) partials[t] = s[t] - v;     // exclusive
}

__global__ void k_scan3(int* __restrict__ offs, const int* __restrict__ partials, int n) {
  int i = blockIdx.x * 256 + threadIdx.x;
  if (i < n) offs[i] += partials[blockIdx.x];
}

__global__ void k_scatter(const int* __restrict__ src, const int* __restrict__ tgt,
                          const int* __restrict__ offs, int* __restrict__ cur,
                          int* __restrict__ csr, int E) {
  int i = blockIdx.x * 256 + threadIdx.x;
  if (i < E) {
    int t = tgt[i];
    int p = atomicAdd(&cur[t], 1);
    csr[offs[t] + p] = src[i];
  }
}

// ---------------- layer 0: aggregate 11-dim input (mean), fp32 ----------------
__global__ void k_agg_in(const float* __restrict__ x, const int* __restrict__ csr,
                         const int* __restrict__ offs, const int* __restrict__ deg,
                         float* __restrict__ out, int n) {
  int t = threadIdx.x;
  int lane = t & 15;
  int node = blockIdx.x * 16 + (t >> 4);
  if (node >= n) return;
  int o = offs[node], d = deg[node];
  float sum = 0.f;
  int e = 0;
  for (; e + 4 <= d; e += 4) {
    int s0 = csr[o + e], s1 = csr[o + e + 1], s2 = csr[o + e + 2], s3 = csr[o + e + 3];
    float v0 = 0.f, v1 = 0.f, v2 = 0.f, v3 = 0.f;
    if (lane < F_IN) {
      v0 = x[(size_t)s0 * F_IN + lane];
      v1 = x[(size_t)s1 * F_IN + lane];
      v2 = x[(size_t)s2 * F_IN + lane];
      v3 = x[(size_t)s3 * F_IN + lane];
    }
    sum += (v0 + v1) + (v2 + v3);
  }
  for (; e < d; ++e) {
    int s = csr[o + e];
    if (lane < F_IN) sum += x[(size_t)s * F_IN + lane];
  }
  float rd = (d > 0) ? 1.f / (float)d : 1.f;
  if (lane < F_IN) out[(size_t)node * F_IN + lane] = sum * rd;
}

// ---------------- layer 0 linear (11->128) + LN + ReLU -> bf16 x1 ----------------
__global__ __launch_bounds__(256) void k_lin0(
    const float* __restrict__ xin, const float* __restrict__ W,
    const float* __restrict__ b, const float* __restrict__ g,
    const float* __restrict__ be, const int* __restrict__ deg,
    unsigned* __restrict__ xout, int n) {     // xout: bf16 packed, 64 uints/row
  __shared__ float Ws[128 * F_IN];
  __shared__ float bs[128], gs[128], bes[128];
  __shared__ float xs[8][F_IN + 1];
  int t = threadIdx.x;
  for (int i = t; i < 128 * F_IN; i += 256) Ws[i] = W[i];
  if (t < 128) { bs[t] = b[t]; gs[t] = g[t]; bes[t] = be[t]; }
  int jg = t & 31, ng = t >> 5;  // 8 nodes per iter, one per 32-lane group
  for (int base = blockIdx.x * 8; base < n; base += gridDim.x * 8) {
    __syncthreads();
    if (t < 8 * F_IN) {
      int r = t / F_IN, c = t % F_IN;
      xs[r][c] = xin[(size_t)(base + r) * F_IN + c];
    }
    __syncthreads();
    int node = base + ng;
    float bm = (deg[node] > 0) ? 1.f : 0.f;
    float acc[4];
#pragma unroll
    for (int i = 0; i < 4; i++) acc[i] = bm * bs[4 * jg + i];
#pragma unroll
    for (int k = 0; k < F_IN; k++) {
      float xv = xs[ng][k];
#pragma unroll
      for (int i = 0; i < 4; i++) acc[i] += xv * Ws[(4 * jg + i) * F_IN + k];
    }
    float s1 = acc[0] + acc[1] + acc[2] + acc[3];
    float s2 = acc[0]*acc[0] + acc[1]*acc[1] + acc[2]*acc[2] + acc[3]*acc[3];
#pragma unroll
    for (int m = 1; m < 32; m <<= 1) {
      s1 += __shfl_xor(s1, m, 64);
      s2 += __shfl_xor(s2, m, 64);
    }
    float mu = s1 * (1.f / 128.f);
    float var = s2 * (1.f / 128.f) - mu * mu;
    float rs = rsqrtf(var + LN_EPS);
    float o[4];
#pragma unroll
    for (int i = 0; i < 4; i++)
      o[i] = fmaxf((acc[i] - mu) * rs * gs[4 * jg + i] + bes[4 * jg + i], 0.f);
    uint2 pk;
    pk.x = (unsigned)f2bf(o[0]) | ((unsigned)f2bf(o[1]) << 16);
    pk.y = (unsigned)f2bf(o[2]) | ((unsigned)f2bf(o[3]) << 16);
    ((uint2*)xout)[(size_t)node * 32 + jg] = pk;   // byte: node*256 + jg*8
  }
}

// ---------------- aggregate 128-dim bf16 (mean) -> bf16, wave per node ----------------
__global__ __launch_bounds__(256) void k_agg128(
    const unsigned* __restrict__ X, const int* __restrict__ csr,
    const int* __restrict__ offs, const int* __restrict__ deg,
    unsigned* __restrict__ out, int n) {
  int t = threadIdx.x;
  int lane = t & 63;
  int node = blockIdx.x * 4 + (t >> 6);
  if (node >= n) return;
  int o = offs[node], d = deg[node];
  float sx = 0.f, sy = 0.f;
  int e = 0;
  for (; e + 4 <= d; e += 4) {
    int s0 = csr[o + e], s1 = csr[o + e + 1], s2 = csr[o + e + 2], s3 = csr[o + e + 3];
    unsigned v0 = X[(size_t)s0 * 64 + lane];
    unsigned v1 = X[(size_t)s1 * 64 + lane];
    unsigned v2 = X[(size_t)s2 * 64 + lane];
    unsigned v3 = X[(size_t)s3 * 64 + lane];
    sx += (bf_lo(v0) + bf_lo(v1)) + (bf_lo(v2) + bf_lo(v3));
    sy += (bf_hi(v0) + bf_hi(v1)) + (bf_hi(v2) + bf_hi(v3));
  }
  for (; e < d; ++e) {
    unsigned v = X[(size_t)csr[o + e] * 64 + lane];
    sx += bf_lo(v);
    sy += bf_hi(v);
  }
  float rd = (d > 0) ? 1.f / (float)d : 1.f;
  unsigned pk = (unsigned)f2bf(sx * rd) | ((unsigned)f2bf(sy * rd) << 16);
  out[(size_t)node * 64 + lane] = pk;
}

// ---------------- fused layer1+layer2 MFMA MLP ----------------
// in : xa  = aggregated x1, bf16 row-major [n][128]  (64 uints/row)
// out: xt2 = (relu(ln(xa@W1t + m*b1)))@W2t + b2, bf16 row-major [n][64] (32 uints/row)
__global__ __launch_bounds__(256) void k_mlp(
    const unsigned* __restrict__ xa,
    const float* __restrict__ W1, const float* __restrict__ b1,
    const float* __restrict__ g1, const float* __restrict__ be1,
    const float* __restrict__ W2, const float* __restrict__ b2,
    const int* __restrict__ deg,
    unsigned* __restrict__ xt2, int n) {
  __shared__ short8 Wf1[32 * 64];        // 32 KB: B-frags, tile = kt*8+nt
  __shared__ short8 Wf2[16 * 64];        // 16 KB: B-frags, tile = kt*4+nt
  __shared__ unsigned bounce[4][1024];   // 4 KB per wave
  int t = threadIdx.x;
  int L = t & 63, w = t >> 6;
  // stage W1 B-fragments: B[n=l&15][k=(l>>4)*8+j] = W1[nt*16+(l&15)][kt*32+(l>>4)*8+j]
  for (int f = t; f < 2048; f += 256) {
    int tile = f >> 6, l = f & 63;
    int kt = tile >> 3, nt = tile & 7;
    const float* p = &W1[(nt * 16 + (l & 15)) * 128 + kt * 32 + (l >> 4) * 8];
    short8 v;
#pragma unroll
    for (int j = 0; j < 8; j++) v[j] = (short)f2bf(p[j]);
    Wf1[f] = v;
  }
  for (int f = t; f < 1024; f += 256) {
    int tile = f >> 6, l = f & 63;
    int kt = tile >> 2, nt = tile & 3;
    const float* p = &W2[(nt * 16 + (l & 15)) * 128 + kt * 32 + (l >> 4) * 8];
    short8 v;
#pragma unroll
    for (int j = 0; j < 8; j++) v[j] = (short)f2bf(p[j]);
    Wf2[f] = v;
  }
  int c = L & 15;
  float b1v[8], g1v[8], be1v[8], b2v[4];
#pragma unroll
  for (int nt = 0; nt < 8; nt++) {
    b1v[nt] = b1[nt * 16 + c];
    g1v[nt] = g1[nt * 16 + c];
    be1v[nt] = be1[nt * 16 + c];
  }
#pragma unroll
  for (int nt = 0; nt < 4; nt++) b2v[nt] = b2[nt * 16 + c];
  __syncthreads();

  int ntiles = n >> 4;                    // n is a multiple of 16
  unsigned* bw = bounce[w];
  int gg0 = (L >> 3) & 1;
  int odd = L & 1;
  for (int tile = blockIdx.x * 4 + w; tile < ntiles; tile += gridDim.x * 4) {
    int m0 = tile << 4;
    // ---- GEMM1: A-frags direct from global (bf16 rm) ----
    short8 a1[4];
    const char* xrow = (const char*)xa + (size_t)(m0 + c) * 256 + (L >> 4) * 16;
#pragma unroll
    for (int kt = 0; kt < 4; kt++) a1[kt] = *(const short8*)(xrow + kt * 64);
    f32x4 acc[8];
#pragma unroll
    for (int nt = 0; nt < 8; nt++) acc[nt] = (f32x4){0.f, 0.f, 0.f, 0.f};
#pragma unroll
    for (int kt = 0; kt < 4; kt++)
#pragma unroll
      for (int nt = 0; nt < 8; nt++)
        acc[nt] = __builtin_amdgcn_mfma_f32_16x16x32_bf16(
            a1[kt], Wf1[(kt * 8 + nt) * 64 + L], acc[nt], 0, 0, 0);
    // deg-masked bias (aggregate-first identity)
    int4 d4 = *(const int4*)&deg[m0 + (L >> 4) * 4];
    float mk[4];
    mk[0] = d4.x > 0 ? 1.f : 0.f; mk[1] = d4.y > 0 ? 1.f : 0.f;
    mk[2] = d4.z > 0 ? 1.f : 0.f; mk[3] = d4.w > 0 ? 1.f : 0.f;
#pragma unroll
    for (int nt = 0; nt < 8; nt++)
#pragma unroll
      for (int r = 0; r < 4; r++) acc[nt][r] += mk[r] * b1v[nt];
    // LN over each node-row (row r lives in 16-lane group, spread over 8 frags)
    float mu[4], rs[4];
#pragma unroll
    for (int r = 0; r < 4; r++) {
      float s1 = 0.f, s2 = 0.f;
#pragma unroll
      for (int nt = 0; nt < 8; nt++) { float v = acc[nt][r]; s1 += v; s2 += v * v; }
#pragma unroll
      for (int m = 1; m < 16; m <<= 1) {
        s1 += __shfl_xor(s1, m, 64);
        s2 += __shfl_xor(s2, m, 64);
      }
      float m_ = s1 * (1.f / 128.f);
      float var = s2 * (1.f / 128.f) - m_ * m_;
      mu[r] = m_;
      rs[r] = rsqrtf(var + LN_EPS);
    }
    // x2 = relu(ln(...)) -> write to bounce in A-frag layout (pairs via lane^1 shfl)
#pragma unroll
    for (int r = 0; r < 4; r++) {
      int rr = (L >> 4) * 4 + r;
#pragma unroll
      for (int p = 0; p < 4; p++) {
        float v0 = fmaxf((acc[2 * p][r] - mu[r]) * rs[r] * g1v[2 * p] + be1v[2 * p], 0.f);
        float v1 = fmaxf((acc[2 * p + 1][r] - mu[r]) * rs[r] * g1v[2 * p + 1] + be1v[2 * p + 1], 0.f);
        float u0 = __shfl_xor(v0, 1, 64);
        float u1 = __shfl_xor(v1, 1, 64);
        float w0 = odd ? u1 : v0;
        float w1 = odd ? v1 : u0;
        unsigned pk = (unsigned)f2bf(w0) | ((unsigned)f2bf(w1) << 16);
        int slot = rr + 16 * (gg0 + (odd ? 2 : 0));
        bw[p * 256 + slot * 4 + ((L & 6) >> 1)] = pk;
      }
    }
    // ---- GEMM2: A-frags from bounce ----
    short8 a2[4];
    const short8* br = (const short8*)bw;
#pragma unroll
    for (int kt = 0; kt < 4; kt++) a2[kt] = br[kt * 64 + L];
    f32x4 acc2[4];
#pragma unroll
    for (int nt = 0; nt < 4; nt++) acc2[nt] = (f32x4){0.f, 0.f, 0.f, 0.f};
#pragma unroll
    for (int kt = 0; kt < 4; kt++)
#pragma unroll
      for (int nt = 0; nt < 4; nt++)
        acc2[nt] = __builtin_amdgcn_mfma_f32_16x16x32_bf16(
            a2[kt], Wf2[(kt * 4 + nt) * 64 + L], acc2[nt], 0, 0, 0);
#pragma unroll
    for (int nt = 0; nt < 4; nt++)
#pragma unroll
      for (int r = 0; r < 4; r++) acc2[nt][r] += b2v[nt];
    // xt2 -> bounce row-major [16][64] bf16, then coalesced global store
#pragma unroll
    for (int r = 0; r < 4; r++) {
      int rr = (L >> 4) * 4 + r;
#pragma unroll
      for (int p = 0; p < 2; p++) {
        float v0 = acc2[2 * p][r], v1 = acc2[2 * p + 1][r];
        float u0 = __shfl_xor(v0, 1, 64);
        float u1 = __shfl_xor(v1, 1, 64);
        float w0 = odd ? u1 : v0;
        float w1 = odd ? v1 : u0;
        unsigned pk = (unsigned)f2bf(w0) | ((unsigned)f2bf(w1) << 16);
        int j2 = 32 * p + (odd ? 16 : 0) + (L & 14);
        bw[rr * 32 + (j2 >> 1)] = pk;
      }
    }
    uint4* gout = (uint4*)((char*)xt2 + (size_t)m0 * 128);
    const uint4* brd = (const uint4*)bw;
    gout[L] = brd[L];
    gout[64 + L] = brd[64 + L];
  }
}

// ---------------- aggregate 64-dim bf16 (mean) + final LN, half-wave/node ----------------
__global__ __launch_bounds__(256) void k_agg64_ln(
    const unsigned* __restrict__ X, const int* __restrict__ csr,
    const int* __restrict__ offs, const int* __restrict__ deg,
    const float* __restrict__ g, const float* __restrict__ be,
    float* __restrict__ out, int n) {
  int t = threadIdx.x;
  int lane = t & 31;
  int node = blockIdx.x * 8 + (t >> 5);
  if (node >= n) return;
  int o = offs[node], d = deg[node];
  float sx = 0.f, sy = 0.f;
  int e = 0;
  for (; e + 4 <= d; e += 4) {
    int s0 = csr[o + e], s1 = csr[o + e + 1], s2 = csr[o + e + 2], s3 = csr[o + e + 3];
    unsigned v0 = X[(size_t)s0 * 32 + lane];
    unsigned v1 = X[(size_t)s1 * 32 + lane];
    unsigned v2 = X[(size_t)s2 * 32 + lane];
    unsigned v3 = X[(size_t)s3 * 32 + lane];
    sx += (bf_lo(v0) + bf_lo(v1)) + (bf_lo(v2) + bf_lo(v3));
    sy += (bf_hi(v0) + bf_hi(v1)) + (bf_hi(v2) + bf_hi(v3));
  }
  for (; e < d; ++e) {
    unsigned v = X[(size_t)csr[o + e] * 32 + lane];
    sx += bf_lo(v);
    sy += bf_hi(v);
  }
  float rd = (d > 0) ? 1.f / (float)d : 1.f;
  float vx = sx * rd, vy = sy * rd;
  float s1 = vx + vy, s2 = vx * vx + vy * vy;
#pragma unroll
  for (int m = 1; m < 32; m <<= 1) {   // stays within the 32-lane half
    s1 += __shfl_xor(s1, m, 64);
    s2 += __shfl_xor(s2, m, 64);
  }
  float mu = s1 * (1.f / 64.f);
  float var = s2 * (1.f / 64.f) - mu * mu;
  float rs = rsqrtf(var + LN_EPS);
  float2 gb = ((const float2*)g)[lane];
  float2 bb = ((const float2*)be)[lane];
  float2 o2;
  o2.x = (vx - mu) * rs * gb.x + bb.x;
  o2.y = (vy - mu) * rs * gb.y + bb.y;
  ((float2*)out)[(size_t)node * 32 + lane] = o2;
}

extern "C" void kernel_launch(void* const* d_in, const int* in_sizes, int n_in,
                              void* d_out, int out_size, void* d_ws, size_t ws_size,
                              hipStream_t stream) {
  const float* nf  = (const float*)d_in[0];
  const int*   ei  = (const int*)d_in[1];
  const float* W0  = (const float*)d_in[2];
  const float* b0  = (const float*)d_in[3];
  const float* W1  = (const float*)d_in[4];
  const float* b1  = (const float*)d_in[5];
  const float* W2  = (const float*)d_in[6];
  const float* b2  = (const float*)d_in[7];
  const float* g0  = (const float*)d_in[8];
  const float* be0 = (const float*)d_in[9];
  const float* g1  = (const float*)d_in[10];
  const float* be1 = (const float*)d_in[11];
  const float* g2  = (const float*)d_in[12];
  const float* be2 = (const float*)d_in[13];
  float* out = (float*)d_out;

  int N = in_sizes[0] / F_IN;   // 100000
  int E = in_sizes[1] / 2;      // 1600000
  const int* src = ei;
  const int* tgt = ei + E;

  char* w = (char*)d_ws;
  auto al = [](size_t x) { return (x + 255) & ~(size_t)255; };
  int* deg      = (int*)w;  w += al((size_t)N * 4);
  int* offs     = (int*)w;  w += al((size_t)N * 4);
  int* cur      = (int*)w;  w += al((size_t)N * 4);
  int* partials = (int*)w;  w += al(4096);
  int* csr      = (int*)w;  w += al((size_t)E * 4);
  float* agg0   = (float*)w;    w += al((size_t)N * F_IN * 4);  // fp32 [N][11]
  unsigned* x1  = (unsigned*)w; w += al((size_t)N * 256);       // bf16 [N][128]
  unsigned* axg = (unsigned*)w; w += al((size_t)N * 256);       // bf16 [N][128]
  unsigned* xt2 = (unsigned*)w; w += al((size_t)N * 128);       // bf16 [N][64]

  hipMemsetAsync(deg, 0, (size_t)N * 4, stream);
  hipMemsetAsync(cur, 0, (size_t)N * 4, stream);

  int nb1 = (N + 255) / 256;   // 391
  k_hist<<<(E + 255) / 256, 256, 0, stream>>>(tgt, deg, E);
  k_scan1<<<nb1, 256, 0, stream>>>(deg, offs, partials, N);
  k_scan2<<<1, 512, 0, stream>>>(partials, nb1);
  k_scan3<<<nb1, 256, 0, stream>>>(offs, partials, N);
  k_scatter<<<(E + 255) / 256, 256, 0, stream>>>(src, tgt, offs, cur, csr, E);

  // layer 0: aggregate-first (11-dim fp32), linear+LN+ReLU -> bf16 x1
  k_agg_in<<<(N + 15) / 16, 256, 0, stream>>>(nf, csr, offs, deg, agg0, N);
  k_lin0<<<1024, 256, 0, stream>>>(agg0, W0, b0, g0, be0, deg, x1, N);

  // layer 1 aggregation: bf16 x1 -> bf16 aggregated (fp32 accumulate)
  k_agg128<<<(N + 3) / 4, 256, 0, stream>>>(x1, csr, offs, deg, axg, N);

  // fused layer1 linear+LN+ReLU + layer2 linear (MFMA) -> bf16 xt2
  k_mlp<<<512, 256, 0, stream>>>(axg, W1, b1, g1, be1, W2, b2, deg, xt2, N);

  // layer 2 aggregation + final LN -> out
  k_agg64_ln<<<(N + 7) / 8, 256, 0, stream>>>(xt2, csr, offs, deg, g2, be2, out, N);
}

// Round 4
// 350.376 us; speedup vs baseline: 2.2467x; 1.3779x over previous
//
#include <hip/hip_runtime.h>

#define F_IN 11
#define LN_EPS 1e-5f
#define BKT_SHIFT 8          // bucket = node >> 8 (256 nodes/bucket); requires N <= 131072
#define BKT_CAP 6144         // LDS edge cache per bucket (avg ~4092 for this graph)

typedef __attribute__((ext_vector_type(8))) short short8;
typedef __attribute__((ext_vector_type(4))) float f32x4;
typedef unsigned long long u64;

__device__ inline unsigned short f2bf(float f) {
  unsigned int u = __float_as_uint(f);
  unsigned int r = u + 0x7fffu + ((u >> 16) & 1u);
  return (unsigned short)(r >> 16);
}
__device__ inline float bf_lo(unsigned v) { return __uint_as_float(v << 16); }
__device__ inline float bf_hi(unsigned v) { return __uint_as_float(v & 0xffff0000u); }

// ---------------- CSR build: bucketed counting sort ----------------
// 1) bucket histogram (LDS-private per block, one global add per (block,bucket))
__global__ __launch_bounds__(256) void k_bhist(const int* __restrict__ tgt,
                                               int* __restrict__ bcnt, int E, int NB) {
  __shared__ int h[512];
  int t = threadIdx.x;
  for (int i = t; i < NB; i += 256) h[i] = 0;
  __syncthreads();
  for (int i = blockIdx.x * 256 + t; i < E; i += gridDim.x * 256)
    atomicAdd(&h[tgt[i] >> BKT_SHIFT], 1);
  __syncthreads();
  for (int i = t; i < NB; i += 256) {
    int c = h[i];
    if (c) atomicAdd(&bcnt[i], c);
  }
}

// 2) exclusive scan of bucket counts -> bucket offsets + cursors
__global__ void k_bscan(const int* __restrict__ bcnt, int* __restrict__ bOffs,
                        int* __restrict__ bcur, int NB) {
  __shared__ int s[512];
  int t = threadIdx.x;
  int v = (t < NB) ? bcnt[t] : 0;
  s[t] = v;
  __syncthreads();
  for (int d = 1; d < 512; d <<= 1) {
    int a = (t >= d) ? s[t - d] : 0;
    __syncthreads();
    s[t] += a;
    __syncthreads();
  }
  if (t < NB) {
    int e = s[t] - v;
    bOffs[t] = e;
    bcur[t] = e;
  }
}

// 3) bin edges into bucket-grouped tmp[] (contiguous runs per bucket per chunk)
__global__ __launch_bounds__(256) void k_bin(const int* __restrict__ src,
                                             const int* __restrict__ tgt,
                                             int* __restrict__ bcur,
                                             u64* __restrict__ tmp, int E, int NB) {
  __shared__ int cnt[512];
  __shared__ int gbase[512];
  int t = threadIdx.x;
  int base = blockIdx.x * 4096;
  for (int i = t; i < NB; i += 256) cnt[i] = 0;
  __syncthreads();
  int sv[16], tv[16], rk[16];
#pragma unroll
  for (int j = 0; j < 16; j++) {
    int idx = base + t + 256 * j;
    if (idx < E) {
      sv[j] = src[idx];
      tv[j] = tgt[idx];
      rk[j] = atomicAdd(&cnt[tv[j] >> BKT_SHIFT], 1);
    }
  }
  __syncthreads();
  for (int i = t; i < NB; i += 256) {
    int c = cnt[i];
    gbase[i] = c ? atomicAdd(&bcur[i], c) : 0;
  }
  __syncthreads();
#pragma unroll
  for (int j = 0; j < 16; j++) {
    int idx = base + t + 256 * j;
    if (idx < E)
      tmp[(size_t)gbase[tv[j] >> BKT_SHIFT] + rk[j]] =
          ((u64)(unsigned)tv[j] << 32) | (unsigned)sv[j];
  }
}

// 4) per-bucket: derive deg/offs locally, scatter csr within the bucket's region
__global__ __launch_bounds__(256) void k_bucket(
    const u64* __restrict__ tmp, const int* __restrict__ bOffs,
    const int* __restrict__ bcnt, int* __restrict__ deg, int* __restrict__ offs,
    int* __restrict__ csr, int N) {
  __shared__ u64 eb[BKT_CAP];
  __shared__ int c1[256], lo[256], c2[256];
  int t = threadIdx.x;
  int b = blockIdx.x;
  int base_node = b << BKT_SHIFT;
  int cnt = bcnt[b], base_e = bOffs[b];
  c1[t] = 0;
  c2[t] = 0;
  for (int i = t; i < cnt && i < BKT_CAP; i += 256) eb[i] = tmp[base_e + i];
  __syncthreads();
  for (int i = t; i < cnt; i += 256) {
    u64 e = (i < BKT_CAP) ? eb[i] : tmp[base_e + i];
    atomicAdd(&c1[((int)(e >> 32)) - base_node], 1);
  }
  __syncthreads();
  int myc = c1[t];
  lo[t] = myc;
  __syncthreads();
  for (int d = 1; d < 256; d <<= 1) {
    int a = (t >= d) ? lo[t - d] : 0;
    __syncthreads();
    lo[t] += a;
    __syncthreads();
  }
  int excl = lo[t] - myc;
  __syncthreads();
  lo[t] = excl;
  __syncthreads();
  int node = base_node + t;
  if (node < N) {
    deg[node] = myc;
    offs[node] = base_e + excl;
  }
  for (int i = t; i < cnt; i += 256) {
    u64 e = (i < BKT_CAP) ? eb[i] : tmp[base_e + i];
    int sv = (int)(e & 0xffffffffu);
    int lt = ((int)(e >> 32)) - base_node;
    int r = atomicAdd(&c2[lt], 1);
    csr[base_e + lo[lt] + r] = sv;
  }
}

// ---------------- layer 0: aggregate 11-dim input (mean), fp32 ----------------
__global__ void k_agg_in(const float* __restrict__ x, const int* __restrict__ csr,
                         const int* __restrict__ offs, const int* __restrict__ deg,
                         float* __restrict__ out, int n) {
  int t = threadIdx.x;
  int lane = t & 15;
  int node = blockIdx.x * 16 + (t >> 4);
  if (node >= n) return;
  int o = offs[node], d = deg[node];
  float sum = 0.f;
  int e = 0;
  for (; e + 4 <= d; e += 4) {
    int s0 = csr[o + e], s1 = csr[o + e + 1], s2 = csr[o + e + 2], s3 = csr[o + e + 3];
    float v0 = 0.f, v1 = 0.f, v2 = 0.f, v3 = 0.f;
    if (lane < F_IN) {
      v0 = x[(size_t)s0 * F_IN + lane];
      v1 = x[(size_t)s1 * F_IN + lane];
      v2 = x[(size_t)s2 * F_IN + lane];
      v3 = x[(size_t)s3 * F_IN + lane];
    }
    sum += (v0 + v1) + (v2 + v3);
  }
  for (; e < d; ++e) {
    int s = csr[o + e];
    if (lane < F_IN) sum += x[(size_t)s * F_IN + lane];
  }
  float rd = (d > 0) ? 1.f / (float)d : 1.f;
  if (lane < F_IN) out[(size_t)node * F_IN + lane] = sum * rd;
}

// ---------------- layer 0 linear (11->128) + LN + ReLU -> bf16 x1 ----------------
__global__ __launch_bounds__(256) void k_lin0(
    const float* __restrict__ xin, const float* __restrict__ W,
    const float* __restrict__ b, const float* __restrict__ g,
    const float* __restrict__ be, const int* __restrict__ deg,
    unsigned* __restrict__ xout, int n) {
  __shared__ float Ws[128 * F_IN];
  __shared__ float bs[128], gs[128], bes[128];
  __shared__ float xs[8][F_IN + 1];
  int t = threadIdx.x;
  for (int i = t; i < 128 * F_IN; i += 256) Ws[i] = W[i];
  if (t < 128) { bs[t] = b[t]; gs[t] = g[t]; bes[t] = be[t]; }
  int jg = t & 31, ng = t >> 5;
  for (int base = blockIdx.x * 8; base < n; base += gridDim.x * 8) {
    __syncthreads();
    if (t < 8 * F_IN) {
      int r = t / F_IN, c = t % F_IN;
      xs[r][c] = xin[(size_t)(base + r) * F_IN + c];
    }
    __syncthreads();
    int node = base + ng;
    float bm = (deg[node] > 0) ? 1.f : 0.f;
    float acc[4];
#pragma unroll
    for (int i = 0; i < 4; i++) acc[i] = bm * bs[4 * jg + i];
#pragma unroll
    for (int k = 0; k < F_IN; k++) {
      float xv = xs[ng][k];
#pragma unroll
      for (int i = 0; i < 4; i++) acc[i] += xv * Ws[(4 * jg + i) * F_IN + k];
    }
    float s1 = acc[0] + acc[1] + acc[2] + acc[3];
    float s2 = acc[0]*acc[0] + acc[1]*acc[1] + acc[2]*acc[2] + acc[3]*acc[3];
#pragma unroll
    for (int m = 1; m < 32; m <<= 1) {
      s1 += __shfl_xor(s1, m, 64);
      s2 += __shfl_xor(s2, m, 64);
    }
    float mu = s1 * (1.f / 128.f);
    float var = s2 * (1.f / 128.f) - mu * mu;
    float rs = rsqrtf(var + LN_EPS);
    float o[4];
#pragma unroll
    for (int i = 0; i < 4; i++)
      o[i] = fmaxf((acc[i] - mu) * rs * gs[4 * jg + i] + bes[4 * jg + i], 0.f);
    uint2 pk;
    pk.x = (unsigned)f2bf(o[0]) | ((unsigned)f2bf(o[1]) << 16);
    pk.y = (unsigned)f2bf(o[2]) | ((unsigned)f2bf(o[3]) << 16);
    ((uint2*)xout)[(size_t)node * 32 + jg] = pk;
  }
}

// ---------------- aggregate 128-dim bf16 (mean) -> bf16, wave per node ----------------
__global__ __launch_bounds__(256) void k_agg128(
    const unsigned* __restrict__ X, const int* __restrict__ csr,
    const int* __restrict__ offs, const int* __restrict__ deg,
    unsigned* __restrict__ out, int n) {
  int t = threadIdx.x;
  int lane = t & 63;
  int node = blockIdx.x * 4 + (t >> 6);
  if (node >= n) return;
  int o = offs[node], d = deg[node];
  float sx = 0.f, sy = 0.f;
  int e = 0;
  for (; e + 4 <= d; e += 4) {
    int s0 = csr[o + e], s1 = csr[o + e + 1], s2 = csr[o + e + 2], s3 = csr[o + e + 3];
    unsigned v0 = X[(size_t)s0 * 64 + lane];
    unsigned v1 = X[(size_t)s1 * 64 + lane];
    unsigned v2 = X[(size_t)s2 * 64 + lane];
    unsigned v3 = X[(size_t)s3 * 64 + lane];
    sx += (bf_lo(v0) + bf_lo(v1)) + (bf_lo(v2) + bf_lo(v3));
    sy += (bf_hi(v0) + bf_hi(v1)) + (bf_hi(v2) + bf_hi(v3));
  }
  for (; e < d; ++e) {
    unsigned v = X[(size_t)csr[o + e] * 64 + lane];
    sx += bf_lo(v);
    sy += bf_hi(v);
  }
  float rd = (d > 0) ? 1.f / (float)d : 1.f;
  unsigned pk = (unsigned)f2bf(sx * rd) | ((unsigned)f2bf(sy * rd) << 16);
  out[(size_t)node * 64 + lane] = pk;
}

// ---------------- fused layer1+layer2 MFMA MLP ----------------
__global__ __launch_bounds__(256) void k_mlp(
    const unsigned* __restrict__ xa,
    const float* __restrict__ W1, const float* __restrict__ b1,
    const float* __restrict__ g1, const float* __restrict__ be1,
    const float* __restrict__ W2, const float* __restrict__ b2,
    const int* __restrict__ deg,
    unsigned* __restrict__ xt2, int n) {
  __shared__ short8 Wf1[32 * 64];
  __shared__ short8 Wf2[16 * 64];
  __shared__ unsigned bounce[4][1024];
  int t = threadIdx.x;
  int L = t & 63, w = t >> 6;
  for (int f = t; f < 2048; f += 256) {
    int tile = f >> 6, l = f & 63;
    int kt = tile >> 3, nt = tile & 7;
    const float* p = &W1[(nt * 16 + (l & 15)) * 128 + kt * 32 + (l >> 4) * 8];
    short8 v;
#pragma unroll
    for (int j = 0; j < 8; j++) v[j] = (short)f2bf(p[j]);
    Wf1[f] = v;
  }
  for (int f = t; f < 1024; f += 256) {
    int tile = f >> 6, l = f & 63;
    int kt = tile >> 2, nt = tile & 3;
    const float* p = &W2[(nt * 16 + (l & 15)) * 128 + kt * 32 + (l >> 4) * 8];
    short8 v;
#pragma unroll
    for (int j = 0; j < 8; j++) v[j] = (short)f2bf(p[j]);
    Wf2[f] = v;
  }
  int c = L & 15;
  float b1v[8], g1v[8], be1v[8], b2v[4];
#pragma unroll
  for (int nt = 0; nt < 8; nt++) {
    b1v[nt] = b1[nt * 16 + c];
    g1v[nt] = g1[nt * 16 + c];
    be1v[nt] = be1[nt * 16 + c];
  }
#pragma unroll
  for (int nt = 0; nt < 4; nt++) b2v[nt] = b2[nt * 16 + c];
  __syncthreads();

  int ntiles = n >> 4;
  unsigned* bw = bounce[w];
  int gg0 = (L >> 3) & 1;
  int odd = L & 1;
  for (int tile = blockIdx.x * 4 + w; tile < ntiles; tile += gridDim.x * 4) {
    int m0 = tile << 4;
    short8 a1[4];
    const char* xrow = (const char*)xa + (size_t)(m0 + c) * 256 + (L >> 4) * 16;
#pragma unroll
    for (int kt = 0; kt < 4; kt++) a1[kt] = *(const short8*)(xrow + kt * 64);
    f32x4 acc[8];
#pragma unroll
    for (int nt = 0; nt < 8; nt++) acc[nt] = (f32x4){0.f, 0.f, 0.f, 0.f};
#pragma unroll
    for (int kt = 0; kt < 4; kt++)
#pragma unroll
      for (int nt = 0; nt < 8; nt++)
        acc[nt] = __builtin_amdgcn_mfma_f32_16x16x32_bf16(
            a1[kt], Wf1[(kt * 8 + nt) * 64 + L], acc[nt], 0, 0, 0);
    int4 d4 = *(const int4*)&deg[m0 + (L >> 4) * 4];
    float mk[4];
    mk[0] = d4.x > 0 ? 1.f : 0.f; mk[1] = d4.y > 0 ? 1.f : 0.f;
    mk[2] = d4.z > 0 ? 1.f : 0.f; mk[3] = d4.w > 0 ? 1.f : 0.f;
#pragma unroll
    for (int nt = 0; nt < 8; nt++)
#pragma unroll
      for (int r = 0; r < 4; r++) acc[nt][r] += mk[r] * b1v[nt];
    float mu[4], rs[4];
#pragma unroll
    for (int r = 0; r < 4; r++) {
      float s1 = 0.f, s2 = 0.f;
#pragma unroll
      for (int nt = 0; nt < 8; nt++) { float v = acc[nt][r]; s1 += v; s2 += v * v; }
#pragma unroll
      for (int m = 1; m < 16; m <<= 1) {
        s1 += __shfl_xor(s1, m, 64);
        s2 += __shfl_xor(s2, m, 64);
      }
      float m_ = s1 * (1.f / 128.f);
      float var = s2 * (1.f / 128.f) - m_ * m_;
      mu[r] = m_;
      rs[r] = rsqrtf(var + LN_EPS);
    }
#pragma unroll
    for (int r = 0; r < 4; r++) {
      int rr = (L >> 4) * 4 + r;
#pragma unroll
      for (int p = 0; p < 4; p++) {
        float v0 = fmaxf((acc[2 * p][r] - mu[r]) * rs[r] * g1v[2 * p] + be1v[2 * p], 0.f);
        float v1 = fmaxf((acc[2 * p + 1][r] - mu[r]) * rs[r] * g1v[2 * p + 1] + be1v[2 * p + 1], 0.f);
        float u0 = __shfl_xor(v0, 1, 64);
        float u1 = __shfl_xor(v1, 1, 64);
        float w0 = odd ? u1 : v0;
        float w1 = odd ? v1 : u0;
        unsigned pk = (unsigned)f2bf(w0) | ((unsigned)f2bf(w1) << 16);
        int slot = rr + 16 * (gg0 + (odd ? 2 : 0));
        bw[p * 256 + slot * 4 + ((L & 6) >> 1)] = pk;
      }
    }
    short8 a2[4];
    const short8* br = (const short8*)bw;
#pragma unroll
    for (int kt = 0; kt < 4; kt++) a2[kt] = br[kt * 64 + L];
    f32x4 acc2[4];
#pragma unroll
    for (int nt = 0; nt < 4; nt++) acc2[nt] = (f32x4){0.f, 0.f, 0.f, 0.f};
#pragma unroll
    for (int kt = 0; kt < 4; kt++)
#pragma unroll
      for (int nt = 0; nt < 4; nt++)
        acc2[nt] = __builtin_amdgcn_mfma_f32_16x16x32_bf16(
            a2[kt], Wf2[(kt * 4 + nt) * 64 + L], acc2[nt], 0, 0, 0);
#pragma unroll
    for (int nt = 0; nt < 4; nt++)
#pragma unroll
      for (int r = 0; r < 4; r++) acc2[nt][r] += b2v[nt];
#pragma unroll
    for (int r = 0; r < 4; r++) {
      int rr = (L >> 4) * 4 + r;
#pragma unroll
      for (int p = 0; p < 2; p++) {
        float v0 = acc2[2 * p][r], v1 = acc2[2 * p + 1][r];
        float u0 = __shfl_xor(v0, 1, 64);
        float u1 = __shfl_xor(v1, 1, 64);
        float w0 = odd ? u1 : v0;
        float w1 = odd ? v1 : u0;
        unsigned pk = (unsigned)f2bf(w0) | ((unsigned)f2bf(w1) << 16);
        int j2 = 32 * p + (odd ? 16 : 0) + (L & 14);
        bw[rr * 32 + (j2 >> 1)] = pk;
      }
    }
    uint4* gout = (uint4*)((char*)xt2 + (size_t)m0 * 128);
    const uint4* brd = (const uint4*)bw;
    gout[L] = brd[L];
    gout[64 + L] = brd[64 + L];
  }
}

// ---------------- aggregate 64-dim bf16 (mean) + final LN, half-wave/node ----------------
__global__ __launch_bounds__(256) void k_agg64_ln(
    const unsigned* __restrict__ X, const int* __restrict__ csr,
    const int* __restrict__ offs, const int* __restrict__ deg,
    const float* __restrict__ g, const float* __restrict__ be,
    float* __restrict__ out, int n) {
  int t = threadIdx.x;
  int lane = t & 31;
  int node = blockIdx.x * 8 + (t >> 5);
  if (node >= n) return;
  int o = offs[node], d = deg[node];
  float sx = 0.f, sy = 0.f;
  int e = 0;
  for (; e + 4 <= d; e += 4) {
    int s0 = csr[o + e], s1 = csr[o + e + 1], s2 = csr[o + e + 2], s3 = csr[o + e + 3];
    unsigned v0 = X[(size_t)s0 * 32 + lane];
    unsigned v1 = X[(size_t)s1 * 32 + lane];
    unsigned v2 = X[(size_t)s2 * 32 + lane];
    unsigned v3 = X[(size_t)s3 * 32 + lane];
    sx += (bf_lo(v0) + bf_lo(v1)) + (bf_lo(v2) + bf_lo(v3));
    sy += (bf_hi(v0) + bf_hi(v1)) + (bf_hi(v2) + bf_hi(v3));
  }
  for (; e < d; ++e) {
    unsigned v = X[(size_t)csr[o + e] * 32 + lane];
    sx += bf_lo(v);
    sy += bf_hi(v);
  }
  float rd = (d > 0) ? 1.f / (float)d : 1.f;
  float vx = sx * rd, vy = sy * rd;
  float s1 = vx + vy, s2 = vx * vx + vy * vy;
#pragma unroll
  for (int m = 1; m < 32; m <<= 1) {
    s1 += __shfl_xor(s1, m, 64);
    s2 += __shfl_xor(s2, m, 64);
  }
  float mu = s1 * (1.f / 64.f);
  float var = s2 * (1.f / 64.f) - mu * mu;
  float rs = rsqrtf(var + LN_EPS);
  float2 gb = ((const float2*)g)[lane];
  float2 bb = ((const float2*)be)[lane];
  float2 o2;
  o2.x = (vx - mu) * rs * gb.x + bb.x;
  o2.y = (vy - mu) * rs * gb.y + bb.y;
  ((float2*)out)[(size_t)node * 32 + lane] = o2;
}

extern "C" void kernel_launch(void* const* d_in, const int* in_sizes, int n_in,
                              void* d_out, int out_size, void* d_ws, size_t ws_size,
                              hipStream_t stream) {
  const float* nf  = (const float*)d_in[0];
  const int*   ei  = (const int*)d_in[1];
  const float* W0  = (const float*)d_in[2];
  const float* b0  = (const float*)d_in[3];
  const float* W1  = (const float*)d_in[4];
  const float* b1  = (const float*)d_in[5];
  const float* W2  = (const float*)d_in[6];
  const float* b2  = (const float*)d_in[7];
  const float* g0  = (const float*)d_in[8];
  const float* be0 = (const float*)d_in[9];
  const float* g1  = (const float*)d_in[10];
  const float* be1 = (const float*)d_in[11];
  const float* g2  = (const float*)d_in[12];
  const float* be2 = (const float*)d_in[13];
  float* out = (float*)d_out;

  int N = in_sizes[0] / F_IN;   // 100000
  int E = in_sizes[1] / 2;      // 1600000
  const int* src = ei;
  const int* tgt = ei + E;
  int NB = (N + 255) >> BKT_SHIFT;        // 391 buckets
  int NCH = (E + 4095) / 4096;            // 391 chunks

  char* w = (char*)d_ws;
  auto al = [](size_t x) { return (x + 255) & ~(size_t)255; };
  int* bcnt     = (int*)w;      w += al(512 * 4);
  int* bOffs    = (int*)w;      w += al(512 * 4);
  int* bcur     = (int*)w;      w += al(512 * 4);
  int* deg      = (int*)w;      w += al((size_t)N * 4);
  int* offs     = (int*)w;      w += al((size_t)N * 4);
  int* csr      = (int*)w;      w += al((size_t)E * 4);
  u64* tmp      = (u64*)w;      w += al((size_t)E * 8);
  float* agg0   = (float*)w;    w += al((size_t)N * F_IN * 4);  // fp32 [N][11]
  unsigned* x1  = (unsigned*)w; w += al((size_t)N * 256);       // bf16 [N][128]
  unsigned* axg = (unsigned*)w; w += al((size_t)N * 256);       // bf16 [N][128]
  unsigned* xt2 = (unsigned*)w; w += al((size_t)N * 128);       // bf16 [N][64]

  hipMemsetAsync(bcnt, 0, 512 * 4, stream);

  // CSR build (bucketed counting sort; also produces deg/offs)
  k_bhist<<<256, 256, 0, stream>>>(tgt, bcnt, E, NB);
  k_bscan<<<1, 512, 0, stream>>>(bcnt, bOffs, bcur, NB);
  k_bin<<<NCH, 256, 0, stream>>>(src, tgt, bcur, tmp, E, NB);
  k_bucket<<<NB, 256, 0, stream>>>(tmp, bOffs, bcnt, deg, offs, csr, N);

  // layer 0: aggregate-first (11-dim fp32), linear+LN+ReLU -> bf16 x1
  k_agg_in<<<(N + 15) / 16, 256, 0, stream>>>(nf, csr, offs, deg, agg0, N);
  k_lin0<<<1024, 256, 0, stream>>>(agg0, W0, b0, g0, be0, deg, x1, N);

  // layer 1 aggregation: bf16 x1 -> bf16 aggregated (fp32 accumulate)
  k_agg128<<<(N + 3) / 4, 256, 0, stream>>>(x1, csr, offs, deg, axg, N);

  // fused layer1 linear+LN+ReLU + layer2 linear (MFMA) -> bf16 xt2
  k_mlp<<<512, 256, 0, stream>>>(axg, W1, b1, g1, be1, W2, b2, deg, xt2, N);

  // layer 2 aggregation + final LN -> out
  k_agg64_ln<<<(N + 7) / 8, 256, 0, stream>>>(xt2, csr, offs, deg, g2, be2, out, N);
}

// Round 5
// 341.812 us; speedup vs baseline: 2.3030x; 1.0251x over previous
//
#include <hip/hip_runtime.h>

#define F_IN 11
#define LN_EPS 1e-5f
#define BKT_SHIFT 8          // bucket = node >> 8 (256 nodes/bucket); requires N <= 131072
#define BKT_CAP 6144         // LDS edge cache per bucket (avg ~4092 for this graph)

typedef __attribute__((ext_vector_type(8))) short short8;
typedef __attribute__((ext_vector_type(4))) float f32x4;
typedef unsigned long long u64;

__device__ inline unsigned short f2bf(float f) {
  unsigned int u = __float_as_uint(f);
  unsigned int r = u + 0x7fffu + ((u >> 16) & 1u);
  return (unsigned short)(r >> 16);
}
__device__ inline float bf_lo(unsigned v) { return __uint_as_float(v << 16); }
__device__ inline float bf_hi(unsigned v) { return __uint_as_float(v & 0xffff0000u); }

// ---------------- CSR build: bucketed counting sort ----------------
__global__ __launch_bounds__(256) void k_bhist(const int* __restrict__ tgt,
                                               int* __restrict__ bcnt, int E, int NB) {
  __shared__ int h[512];
  int t = threadIdx.x;
  for (int i = t; i < NB; i += 256) h[i] = 0;
  __syncthreads();
  for (int i = blockIdx.x * 256 + t; i < E; i += gridDim.x * 256)
    atomicAdd(&h[tgt[i] >> BKT_SHIFT], 1);
  __syncthreads();
  for (int i = t; i < NB; i += 256) {
    int c = h[i];
    if (c) atomicAdd(&bcnt[i], c);
  }
}

__global__ void k_bscan(const int* __restrict__ bcnt, int* __restrict__ bOffs,
                        int* __restrict__ bcur, int NB) {
  __shared__ int s[512];
  int t = threadIdx.x;
  int v = (t < NB) ? bcnt[t] : 0;
  s[t] = v;
  __syncthreads();
  for (int d = 1; d < 512; d <<= 1) {
    int a = (t >= d) ? s[t - d] : 0;
    __syncthreads();
    s[t] += a;
    __syncthreads();
  }
  if (t < NB) {
    int e = s[t] - v;
    bOffs[t] = e;
    bcur[t] = e;
  }
}

__global__ __launch_bounds__(256) void k_bin(const int* __restrict__ src,
                                             const int* __restrict__ tgt,
                                             int* __restrict__ bcur,
                                             u64* __restrict__ tmp, int E, int NB) {
  __shared__ int cnt[512];
  __shared__ int gbase[512];
  int t = threadIdx.x;
  int base = blockIdx.x * 4096;
  for (int i = t; i < NB; i += 256) cnt[i] = 0;
  __syncthreads();
  int sv[16], tv[16], rk[16];
#pragma unroll
  for (int j = 0; j < 16; j++) {
    int idx = base + t + 256 * j;
    if (idx < E) {
      sv[j] = src[idx];
      tv[j] = tgt[idx];
      rk[j] = atomicAdd(&cnt[tv[j] >> BKT_SHIFT], 1);
    }
  }
  __syncthreads();
  for (int i = t; i < NB; i += 256) {
    int c = cnt[i];
    gbase[i] = c ? atomicAdd(&bcur[i], c) : 0;
  }
  __syncthreads();
#pragma unroll
  for (int j = 0; j < 16; j++) {
    int idx = base + t + 256 * j;
    if (idx < E)
      tmp[(size_t)gbase[tv[j] >> BKT_SHIFT] + rk[j]] =
          ((u64)(unsigned)tv[j] << 32) | (unsigned)sv[j];
  }
}

__global__ __launch_bounds__(256) void k_bucket(
    const u64* __restrict__ tmp, const int* __restrict__ bOffs,
    const int* __restrict__ bcnt, int* __restrict__ deg, int* __restrict__ offs,
    int* __restrict__ csr, int N) {
  __shared__ u64 eb[BKT_CAP];
  __shared__ int c1[256], lo[256], c2[256];
  int t = threadIdx.x;
  int b = blockIdx.x;
  int base_node = b << BKT_SHIFT;
  int cnt = bcnt[b], base_e = bOffs[b];
  c1[t] = 0;
  c2[t] = 0;
  for (int i = t; i < cnt && i < BKT_CAP; i += 256) eb[i] = tmp[base_e + i];
  __syncthreads();
  for (int i = t; i < cnt; i += 256) {
    u64 e = (i < BKT_CAP) ? eb[i] : tmp[base_e + i];
    atomicAdd(&c1[((int)(e >> 32)) - base_node], 1);
  }
  __syncthreads();
  int myc = c1[t];
  lo[t] = myc;
  __syncthreads();
  for (int d = 1; d < 256; d <<= 1) {
    int a = (t >= d) ? lo[t - d] : 0;
    __syncthreads();
    lo[t] += a;
    __syncthreads();
  }
  int excl = lo[t] - myc;
  __syncthreads();
  lo[t] = excl;
  __syncthreads();
  int node = base_node + t;
  if (node < N) {
    deg[node] = myc;
    offs[node] = base_e + excl;
  }
  for (int i = t; i < cnt; i += 256) {
    u64 e = (i < BKT_CAP) ? eb[i] : tmp[base_e + i];
    int sv = (int)(e & 0xffffffffu);
    int lt = ((int)(e >> 32)) - base_node;
    int r = atomicAdd(&c2[lt], 1);
    csr[base_e + lo[lt] + r] = sv;
  }
}

// ---------------- fused layer 0: aggregate 11-dim + linear(11->128)+LN+ReLU -> bf16 x1 ----------------
__global__ __launch_bounds__(256) void k_l0(
    const float* __restrict__ x, const int* __restrict__ csr,
    const int* __restrict__ offs, const int* __restrict__ deg,
    const float* __restrict__ W, const float* __restrict__ b,
    const float* __restrict__ g, const float* __restrict__ be,
    unsigned* __restrict__ xout, int n) {
  __shared__ float Ws[128 * F_IN];
  __shared__ float bs[128], gs[128], bes[128];
  __shared__ float xs[8][F_IN + 1];
  int t = threadIdx.x;
  for (int i = t; i < 128 * F_IN; i += 256) Ws[i] = W[i];
  if (t < 128) { bs[t] = b[t]; gs[t] = g[t]; bes[t] = be[t]; }
  int jg = t & 31, ng = t >> 5;            // 8 nodes per iter, 32-lane group per node
  int li = t & 15, sub = (t >> 4) & 1;     // 2 edges per step within a group
  for (int base = blockIdx.x * 8; base < n; base += gridDim.x * 8) {
    int node = base + ng;
    int o = offs[node], d = deg[node];
    // aggregate: lanes li<11 of each 16-lane half load a row; sub picks the edge
    float sA = 0.f, sB = 0.f;
    int e = 0;
    for (; e + 4 <= d; e += 4) {
      int i0 = csr[o + e + sub];
      int i1 = csr[o + e + 2 + sub];
      float v0 = 0.f, v1 = 0.f;
      if (li < F_IN) {
        v0 = x[(size_t)i0 * F_IN + li];
        v1 = x[(size_t)i1 * F_IN + li];
      }
      sA += v0;
      sB += v1;
    }
    for (; e < d; e += 2) {
      if (e + sub < d) {
        int i0 = csr[o + e + sub];
        if (li < F_IN) sA += x[(size_t)i0 * F_IN + li];
      }
    }
    float sum = (sA + sB);
    sum += __shfl_xor(sum, 16, 64);        // combine sub halves
    float rd = (d > 0) ? 1.f / (float)d : 1.f;
    __syncthreads();
    if (li < F_IN && sub == 0) xs[ng][li] = sum * rd;
    __syncthreads();
    // linear 11->128 + LN + ReLU
    float bm = (d > 0) ? 1.f : 0.f;
    float acc[4];
#pragma unroll
    for (int i = 0; i < 4; i++) acc[i] = bm * bs[4 * jg + i];
#pragma unroll
    for (int k = 0; k < F_IN; k++) {
      float xv = xs[ng][k];
#pragma unroll
      for (int i = 0; i < 4; i++) acc[i] += xv * Ws[(4 * jg + i) * F_IN + k];
    }
    float s1 = acc[0] + acc[1] + acc[2] + acc[3];
    float s2 = acc[0]*acc[0] + acc[1]*acc[1] + acc[2]*acc[2] + acc[3]*acc[3];
#pragma unroll
    for (int m = 1; m < 32; m <<= 1) {
      s1 += __shfl_xor(s1, m, 64);
      s2 += __shfl_xor(s2, m, 64);
    }
    float mu = s1 * (1.f / 128.f);
    float var = s2 * (1.f / 128.f) - mu * mu;
    float rs = rsqrtf(var + LN_EPS);
    float o4[4];
#pragma unroll
    for (int i = 0; i < 4; i++)
      o4[i] = fmaxf((acc[i] - mu) * rs * gs[4 * jg + i] + bes[4 * jg + i], 0.f);
    uint2 pk;
    pk.x = (unsigned)f2bf(o4[0]) | ((unsigned)f2bf(o4[1]) << 16);
    pk.y = (unsigned)f2bf(o4[2]) | ((unsigned)f2bf(o4[3]) << 16);
    ((uint2*)xout)[(size_t)node * 32 + jg] = pk;
  }
}

// ---------------- aggregate 128-dim bf16 (mean) -> bf16, wave/node, 2 edges/load ----------------
__global__ __launch_bounds__(256) void k_agg128(
    const unsigned* __restrict__ X, const int* __restrict__ csr,
    const int* __restrict__ offs, const int* __restrict__ deg,
    unsigned* __restrict__ out, int n) {
  int t = threadIdx.x;
  int lane = t & 63;
  int half = lane >> 5, li = lane & 31;    // half-wave per row, uint2 covers cols 4li..4li+3
  int node = blockIdx.x * 4 + (t >> 6);
  if (node >= n) return;
  int o = offs[node], d = deg[node];
  const uint2* X2 = (const uint2*)X;
  f32x4 a0 = {0.f, 0.f, 0.f, 0.f}, a1 = {0.f, 0.f, 0.f, 0.f};
  int e = 0;
  for (; e + 8 <= d; e += 8) {
    int i0 = csr[o + e + half];
    int i1 = csr[o + e + 2 + half];
    int i2 = csr[o + e + 4 + half];
    int i3 = csr[o + e + 6 + half];
    uint2 v0 = X2[(size_t)i0 * 32 + li];
    uint2 v1 = X2[(size_t)i1 * 32 + li];
    uint2 v2 = X2[(size_t)i2 * 32 + li];
    uint2 v3 = X2[(size_t)i3 * 32 + li];
    a0[0] += bf_lo(v0.x); a0[1] += bf_hi(v0.x); a0[2] += bf_lo(v0.y); a0[3] += bf_hi(v0.y);
    a1[0] += bf_lo(v1.x); a1[1] += bf_hi(v1.x); a1[2] += bf_lo(v1.y); a1[3] += bf_hi(v1.y);
    a0[0] += bf_lo(v2.x); a0[1] += bf_hi(v2.x); a0[2] += bf_lo(v2.y); a0[3] += bf_hi(v2.y);
    a1[0] += bf_lo(v3.x); a1[1] += bf_hi(v3.x); a1[2] += bf_lo(v3.y); a1[3] += bf_hi(v3.y);
  }
  for (; e < d; e += 2) {
    if (e + half < d) {
      int i0 = csr[o + e + half];
      uint2 v = X2[(size_t)i0 * 32 + li];
      a0[0] += bf_lo(v.x); a0[1] += bf_hi(v.x); a0[2] += bf_lo(v.y); a0[3] += bf_hi(v.y);
    }
  }
#pragma unroll
  for (int i = 0; i < 4; i++) {
    a0[i] += a1[i];
    a0[i] += __shfl_xor(a0[i], 32, 64);
  }
  float rd = (d > 0) ? 1.f / (float)d : 1.f;
  if (half == 0) {
    uint2 pk;
    pk.x = (unsigned)f2bf(a0[0] * rd) | ((unsigned)f2bf(a0[1] * rd) << 16);
    pk.y = (unsigned)f2bf(a0[2] * rd) | ((unsigned)f2bf(a0[3] * rd) << 16);
    ((uint2*)out)[(size_t)node * 32 + li] = pk;
  }
}

// ---------------- fused layer1+layer2 MFMA MLP ----------------
__global__ __launch_bounds__(256) void k_mlp(
    const unsigned* __restrict__ xa,
    const float* __restrict__ W1, const float* __restrict__ b1,
    const float* __restrict__ g1, const float* __restrict__ be1,
    const float* __restrict__ W2, const float* __restrict__ b2,
    const int* __restrict__ deg,
    unsigned* __restrict__ xt2, int n) {
  __shared__ short8 Wf1[32 * 64];
  __shared__ short8 Wf2[16 * 64];
  __shared__ unsigned bounce[4][1024];
  int t = threadIdx.x;
  int L = t & 63, w = t >> 6;
  for (int f = t; f < 2048; f += 256) {
    int tile = f >> 6, l = f & 63;
    int kt = tile >> 3, nt = tile & 7;
    const float* p = &W1[(nt * 16 + (l & 15)) * 128 + kt * 32 + (l >> 4) * 8];
    short8 v;
#pragma unroll
    for (int j = 0; j < 8; j++) v[j] = (short)f2bf(p[j]);
    Wf1[f] = v;
  }
  for (int f = t; f < 1024; f += 256) {
    int tile = f >> 6, l = f & 63;
    int kt = tile >> 2, nt = tile & 3;
    const float* p = &W2[(nt * 16 + (l & 15)) * 128 + kt * 32 + (l >> 4) * 8];
    short8 v;
#pragma unroll
    for (int j = 0; j < 8; j++) v[j] = (short)f2bf(p[j]);
    Wf2[f] = v;
  }
  int c = L & 15;
  float b1v[8], g1v[8], be1v[8], b2v[4];
#pragma unroll
  for (int nt = 0; nt < 8; nt++) {
    b1v[nt] = b1[nt * 16 + c];
    g1v[nt] = g1[nt * 16 + c];
    be1v[nt] = be1[nt * 16 + c];
  }
#pragma unroll
  for (int nt = 0; nt < 4; nt++) b2v[nt] = b2[nt * 16 + c];
  __syncthreads();

  int ntiles = n >> 4;
  unsigned* bw = bounce[w];
  int gg0 = (L >> 3) & 1;
  int odd = L & 1;
  for (int tile = blockIdx.x * 4 + w; tile < ntiles; tile += gridDim.x * 4) {
    int m0 = tile << 4;
    short8 a1[4];
    const char* xrow = (const char*)xa + (size_t)(m0 + c) * 256 + (L >> 4) * 16;
#pragma unroll
    for (int kt = 0; kt < 4; kt++) a1[kt] = *(const short8*)(xrow + kt * 64);
    f32x4 acc[8];
#pragma unroll
    for (int nt = 0; nt < 8; nt++) acc[nt] = (f32x4){0.f, 0.f, 0.f, 0.f};
#pragma unroll
    for (int kt = 0; kt < 4; kt++)
#pragma unroll
      for (int nt = 0; nt < 8; nt++)
        acc[nt] = __builtin_amdgcn_mfma_f32_16x16x32_bf16(
            a1[kt], Wf1[(kt * 8 + nt) * 64 + L], acc[nt], 0, 0, 0);
    int4 d4 = *(const int4*)&deg[m0 + (L >> 4) * 4];
    float mk[4];
    mk[0] = d4.x > 0 ? 1.f : 0.f; mk[1] = d4.y > 0 ? 1.f : 0.f;
    mk[2] = d4.z > 0 ? 1.f : 0.f; mk[3] = d4.w > 0 ? 1.f : 0.f;
#pragma unroll
    for (int nt = 0; nt < 8; nt++)
#pragma unroll
      for (int r = 0; r < 4; r++) acc[nt][r] += mk[r] * b1v[nt];
    float mu[4], rs[4];
#pragma unroll
    for (int r = 0; r < 4; r++) {
      float s1 = 0.f, s2 = 0.f;
#pragma unroll
      for (int nt = 0; nt < 8; nt++) { float v = acc[nt][r]; s1 += v; s2 += v * v; }
#pragma unroll
      for (int m = 1; m < 16; m <<= 1) {
        s1 += __shfl_xor(s1, m, 64);
        s2 += __shfl_xor(s2, m, 64);
      }
      float m_ = s1 * (1.f / 128.f);
      float var = s2 * (1.f / 128.f) - m_ * m_;
      mu[r] = m_;
      rs[r] = rsqrtf(var + LN_EPS);
    }
#pragma unroll
    for (int r = 0; r < 4; r++) {
      int rr = (L >> 4) * 4 + r;
#pragma unroll
      for (int p = 0; p < 4; p++) {
        float v0 = fmaxf((acc[2 * p][r] - mu[r]) * rs[r] * g1v[2 * p] + be1v[2 * p], 0.f);
        float v1 = fmaxf((acc[2 * p + 1][r] - mu[r]) * rs[r] * g1v[2 * p + 1] + be1v[2 * p + 1], 0.f);
        float u0 = __shfl_xor(v0, 1, 64);
        float u1 = __shfl_xor(v1, 1, 64);
        float w0 = odd ? u1 : v0;
        float w1 = odd ? v1 : u0;
        unsigned pk = (unsigned)f2bf(w0) | ((unsigned)f2bf(w1) << 16);
        int slot = rr + 16 * (gg0 + (odd ? 2 : 0));
        bw[p * 256 + slot * 4 + ((L & 6) >> 1)] = pk;
      }
    }
    short8 a2[4];
    const short8* br = (const short8*)bw;
#pragma unroll
    for (int kt = 0; kt < 4; kt++) a2[kt] = br[kt * 64 + L];
    f32x4 acc2[4];
#pragma unroll
    for (int nt = 0; nt < 4; nt++) acc2[nt] = (f32x4){0.f, 0.f, 0.f, 0.f};
#pragma unroll
    for (int kt = 0; kt < 4; kt++)
#pragma unroll
      for (int nt = 0; nt < 4; nt++)
        acc2[nt] = __builtin_amdgcn_mfma_f32_16x16x32_bf16(
            a2[kt], Wf2[(kt * 4 + nt) * 64 + L], acc2[nt], 0, 0, 0);
#pragma unroll
    for (int nt = 0; nt < 4; nt++)
#pragma unroll
      for (int r = 0; r < 4; r++) acc2[nt][r] += b2v[nt];
#pragma unroll
    for (int r = 0; r < 4; r++) {
      int rr = (L >> 4) * 4 + r;
#pragma unroll
      for (int p = 0; p < 2; p++) {
        float v0 = acc2[2 * p][r], v1 = acc2[2 * p + 1][r];
        float u0 = __shfl_xor(v0, 1, 64);
        float u1 = __shfl_xor(v1, 1, 64);
        float w0 = odd ? u1 : v0;
        float w1 = odd ? v1 : u0;
        unsigned pk = (unsigned)f2bf(w0) | ((unsigned)f2bf(w1) << 16);
        int j2 = 32 * p + (odd ? 16 : 0) + (L & 14);
        bw[rr * 32 + (j2 >> 1)] = pk;
      }
    }
    uint4* gout = (uint4*)((char*)xt2 + (size_t)m0 * 128);
    const uint4* brd = (const uint4*)bw;
    gout[L] = brd[L];
    gout[64 + L] = brd[64 + L];
  }
}

// ---------------- aggregate 64-dim bf16 (mean) + final LN, 2 edges/load ----------------
__global__ __launch_bounds__(256) void k_agg64_ln(
    const unsigned* __restrict__ X, const int* __restrict__ csr,
    const int* __restrict__ offs, const int* __restrict__ deg,
    const float* __restrict__ g, const float* __restrict__ be,
    float* __restrict__ out, int n) {
  int t = threadIdx.x;
  int lane = t & 31;                       // 32-lane group per node
  int sub = lane >> 4, li = lane & 15;     // 16-lane quarter per row, uint2 covers cols 4li..4li+3
  int node = blockIdx.x * 8 + (t >> 5);
  if (node >= n) return;
  int o = offs[node], d = deg[node];
  const uint2* X2 = (const uint2*)X;
  f32x4 a0 = {0.f, 0.f, 0.f, 0.f}, a1 = {0.f, 0.f, 0.f, 0.f};
  int e = 0;
  for (; e + 8 <= d; e += 8) {
    int i0 = csr[o + e + sub];
    int i1 = csr[o + e + 2 + sub];
    int i2 = csr[o + e + 4 + sub];
    int i3 = csr[o + e + 6 + sub];
    uint2 v0 = X2[(size_t)i0 * 16 + li];
    uint2 v1 = X2[(size_t)i1 * 16 + li];
    uint2 v2 = X2[(size_t)i2 * 16 + li];
    uint2 v3 = X2[(size_t)i3 * 16 + li];
    a0[0] += bf_lo(v0.x); a0[1] += bf_hi(v0.x); a0[2] += bf_lo(v0.y); a0[3] += bf_hi(v0.y);
    a1[0] += bf_lo(v1.x); a1[1] += bf_hi(v1.x); a1[2] += bf_lo(v1.y); a1[3] += bf_hi(v1.y);
    a0[0] += bf_lo(v2.x); a0[1] += bf_hi(v2.x); a0[2] += bf_lo(v2.y); a0[3] += bf_hi(v2.y);
    a1[0] += bf_lo(v3.x); a1[1] += bf_hi(v3.x); a1[2] += bf_lo(v3.y); a1[3] += bf_hi(v3.y);
  }
  for (; e < d; e += 2) {
    if (e + sub < d) {
      int i0 = csr[o + e + sub];
      uint2 v = X2[(size_t)i0 * 16 + li];
      a0[0] += bf_lo(v.x); a0[1] += bf_hi(v.x); a0[2] += bf_lo(v.y); a0[3] += bf_hi(v.y);
    }
  }
  float rd = (d > 0) ? 1.f / (float)d : 1.f;
  float v4[4];
#pragma unroll
  for (int i = 0; i < 4; i++) {
    a0[i] += a1[i];
    a0[i] += __shfl_xor(a0[i], 16, 64);    // combine sub quarters (within 32-group)
    v4[i] = a0[i] * rd;
  }
  float s1 = (v4[0] + v4[1]) + (v4[2] + v4[3]);
  float s2 = (v4[0]*v4[0] + v4[1]*v4[1]) + (v4[2]*v4[2] + v4[3]*v4[3]);
#pragma unroll
  for (int m = 1; m < 16; m <<= 1) {       // reduce over the 16 li lanes
    s1 += __shfl_xor(s1, m, 64);
    s2 += __shfl_xor(s2, m, 64);
  }
  float mu = s1 * (1.f / 64.f);
  float var = s2 * (1.f / 64.f) - mu * mu;
  float rs = rsqrtf(var + LN_EPS);
  if (sub == 0) {
    float4 gb = *(const float4*)&g[4 * li];
    float4 bb = *(const float4*)&be[4 * li];
    float4 o4;
    o4.x = (v4[0] - mu) * rs * gb.x + bb.x;
    o4.y = (v4[1] - mu) * rs * gb.y + bb.y;
    o4.z = (v4[2] - mu) * rs * gb.z + bb.z;
    o4.w = (v4[3] - mu) * rs * gb.w + bb.w;
    *(float4*)&out[(size_t)node * 64 + 4 * li] = o4;
  }
}

extern "C" void kernel_launch(void* const* d_in, const int* in_sizes, int n_in,
                              void* d_out, int out_size, void* d_ws, size_t ws_size,
                              hipStream_t stream) {
  const float* nf  = (const float*)d_in[0];
  const int*   ei  = (const int*)d_in[1];
  const float* W0  = (const float*)d_in[2];
  const float* b0  = (const float*)d_in[3];
  const float* W1  = (const float*)d_in[4];
  const float* b1  = (const float*)d_in[5];
  const float* W2  = (const float*)d_in[6];
  const float* b2  = (const float*)d_in[7];
  const float* g0  = (const float*)d_in[8];
  const float* be0 = (const float*)d_in[9];
  const float* g1  = (const float*)d_in[10];
  const float* be1 = (const float*)d_in[11];
  const float* g2  = (const float*)d_in[12];
  const float* be2 = (const float*)d_in[13];
  float* out = (float*)d_out;

  int N = in_sizes[0] / F_IN;   // 100000
  int E = in_sizes[1] / 2;      // 1600000
  const int* src = ei;
  const int* tgt = ei + E;
  int NB = (N + 255) >> BKT_SHIFT;        // 391 buckets
  int NCH = (E + 4095) / 4096;            // 391 chunks

  char* w = (char*)d_ws;
  auto al = [](size_t x) { return (x + 255) & ~(size_t)255; };
  int* bcnt     = (int*)w;      w += al(512 * 4);
  int* bOffs    = (int*)w;      w += al(512 * 4);
  int* bcur     = (int*)w;      w += al(512 * 4);
  int* deg      = (int*)w;      w += al((size_t)N * 4);
  int* offs     = (int*)w;      w += al((size_t)N * 4);
  int* csr      = (int*)w;      w += al((size_t)E * 4);
  u64* tmp      = (u64*)w;      w += al((size_t)E * 8);
  unsigned* x1  = (unsigned*)w; w += al((size_t)N * 256);       // bf16 [N][128]
  unsigned* axg = (unsigned*)w; w += al((size_t)N * 256);       // bf16 [N][128]
  unsigned* xt2 = (unsigned*)w; w += al((size_t)N * 128);       // bf16 [N][64]

  hipMemsetAsync(bcnt, 0, 512 * 4, stream);

  // CSR build (bucketed counting sort; also produces deg/offs)
  k_bhist<<<256, 256, 0, stream>>>(tgt, bcnt, E, NB);
  k_bscan<<<1, 512, 0, stream>>>(bcnt, bOffs, bcur, NB);
  k_bin<<<NCH, 256, 0, stream>>>(src, tgt, bcur, tmp, E, NB);
  k_bucket<<<NB, 256, 0, stream>>>(tmp, bOffs, bcnt, deg, offs, csr, N);

  // layer 0 fused: aggregate (11-dim fp32) + linear+LN+ReLU -> bf16 x1
  k_l0<<<(N + 7) / 8, 256, 0, stream>>>(nf, csr, offs, deg, W0, b0, g0, be0, x1, N);

  // layer 1 aggregation: bf16 x1 -> bf16 aggregated (fp32 accumulate)
  k_agg128<<<(N + 3) / 4, 256, 0, stream>>>(x1, csr, offs, deg, axg, N);

  // fused layer1 linear+LN+ReLU + layer2 linear (MFMA) -> bf16 xt2
  k_mlp<<<512, 256, 0, stream>>>(axg, W1, b1, g1, be1, W2, b2, deg, xt2, N);

  // layer 2 aggregation + final LN -> out
  k_agg64_ln<<<(N + 7) / 8, 256, 0, stream>>>(xt2, csr, offs, deg, g2, be2, out, N);
}

// Round 6
// 328.338 us; speedup vs baseline: 2.3975x; 1.0410x over previous
//
#include <hip/hip_runtime.h>

#define F_IN 11
#define LN_EPS 1e-5f
#define BKT_SHIFT 8          // bucket = node >> 8 (256 nodes/bucket); requires N <= 131072
#define BKT_CAP 6144         // LDS edge cache per bucket (avg ~4092 for this graph)

typedef __attribute__((ext_vector_type(8))) short short8;
typedef __attribute__((ext_vector_type(4))) float f32x4;
typedef unsigned long long u64;

__device__ inline unsigned short f2bf(float f) {
  unsigned int u = __float_as_uint(f);
  unsigned int r = u + 0x7fffu + ((u >> 16) & 1u);
  return (unsigned short)(r >> 16);
}
__device__ inline float bf_lo(unsigned v) { return __uint_as_float(v << 16); }
__device__ inline float bf_hi(unsigned v) { return __uint_as_float(v & 0xffff0000u); }

#define ACC8(A, V) \
  A[0] += bf_lo(V.x); A[1] += bf_hi(V.x); A[2] += bf_lo(V.y); A[3] += bf_hi(V.y); \
  A[4] += bf_lo(V.z); A[5] += bf_hi(V.z); A[6] += bf_lo(V.w); A[7] += bf_hi(V.w);

// ---------------- CSR build: bucketed counting sort ----------------
__global__ __launch_bounds__(256) void k_bhist(const int* __restrict__ tgt,
                                               int* __restrict__ bcnt, int E, int NB) {
  __shared__ int h[512];
  int t = threadIdx.x;
  for (int i = t; i < NB; i += 256) h[i] = 0;
  __syncthreads();
  for (int i = blockIdx.x * 256 + t; i < E; i += gridDim.x * 256)
    atomicAdd(&h[tgt[i] >> BKT_SHIFT], 1);
  __syncthreads();
  for (int i = t; i < NB; i += 256) {
    int c = h[i];
    if (c) atomicAdd(&bcnt[i], c);
  }
}

__global__ void k_bscan(const int* __restrict__ bcnt, int* __restrict__ bOffs,
                        int* __restrict__ bcur, int NB) {
  __shared__ int s[512];
  int t = threadIdx.x;
  int v = (t < NB) ? bcnt[t] : 0;
  s[t] = v;
  __syncthreads();
  for (int d = 1; d < 512; d <<= 1) {
    int a = (t >= d) ? s[t - d] : 0;
    __syncthreads();
    s[t] += a;
    __syncthreads();
  }
  if (t < NB) {
    int e = s[t] - v;
    bOffs[t] = e;
    bcur[t] = e;
  }
}

// pack: (tgt & 255) << 24 | src   (needs src < 2^24, N <= 2^24)
__global__ __launch_bounds__(256) void k_bin(const int* __restrict__ src,
                                             const int* __restrict__ tgt,
                                             int* __restrict__ bcur,
                                             unsigned* __restrict__ tmp, int E, int NB) {
  __shared__ int cnt[512];
  __shared__ int gbase[512];
  int t = threadIdx.x;
  int base = blockIdx.x * 4096;
  for (int i = t; i < NB; i += 256) cnt[i] = 0;
  __syncthreads();
  int sv[16], tv[16], rk[16];
#pragma unroll
  for (int j = 0; j < 16; j++) {
    int idx = base + t + 256 * j;
    if (idx < E) {
      sv[j] = src[idx];
      tv[j] = tgt[idx];
      rk[j] = atomicAdd(&cnt[tv[j] >> BKT_SHIFT], 1);
    }
  }
  __syncthreads();
  for (int i = t; i < NB; i += 256) {
    int c = cnt[i];
    gbase[i] = c ? atomicAdd(&bcur[i], c) : 0;
  }
  __syncthreads();
#pragma unroll
  for (int j = 0; j < 16; j++) {
    int idx = base + t + 256 * j;
    if (idx < E)
      tmp[(size_t)gbase[tv[j] >> BKT_SHIFT] + rk[j]] =
          ((unsigned)(tv[j] & 255) << 24) | (unsigned)sv[j];
  }
}

__global__ __launch_bounds__(256) void k_bucket(
    const unsigned* __restrict__ tmp, const int* __restrict__ bOffs,
    const int* __restrict__ bcnt, int* __restrict__ deg, int* __restrict__ offs,
    int* __restrict__ csr, int N) {
  __shared__ unsigned eb[BKT_CAP];
  __shared__ int c1[256], lo[256], c2[256];
  int t = threadIdx.x;
  int b = blockIdx.x;
  int base_node = b << BKT_SHIFT;
  int cnt = bcnt[b], base_e = bOffs[b];
  c1[t] = 0;
  c2[t] = 0;
  for (int i = t; i < cnt && i < BKT_CAP; i += 256) eb[i] = tmp[base_e + i];
  __syncthreads();
  for (int i = t; i < cnt; i += 256) {
    unsigned e = (i < BKT_CAP) ? eb[i] : tmp[base_e + i];
    atomicAdd(&c1[e >> 24], 1);
  }
  __syncthreads();
  int myc = c1[t];
  lo[t] = myc;
  __syncthreads();
  for (int d = 1; d < 256; d <<= 1) {
    int a = (t >= d) ? lo[t - d] : 0;
    __syncthreads();
    lo[t] += a;
    __syncthreads();
  }
  int excl = lo[t] - myc;
  __syncthreads();
  lo[t] = excl;
  __syncthreads();
  int node = base_node + t;
  if (node < N) {
    deg[node] = myc;
    offs[node] = base_e + excl;
  }
  for (int i = t; i < cnt; i += 256) {
    unsigned e = (i < BKT_CAP) ? eb[i] : tmp[base_e + i];
    int sv = (int)(e & 0xffffffu);
    int lt = e >> 24;
    int r = atomicAdd(&c2[lt], 1);
    csr[base_e + lo[lt] + r] = sv;
  }
}

// ---------------- convert node features -> bf16 padded [N][16] (8 uints/row) ----------------
__global__ __launch_bounds__(256) void k_cvt(const float* __restrict__ nf,
                                             unsigned* __restrict__ nfb, int n) {
  int t = blockIdx.x * 256 + threadIdx.x;
  int node = t >> 3, li8 = t & 7;
  if (node >= n) return;
  int c0 = 2 * li8;
  float v0 = (c0 < F_IN) ? nf[(size_t)node * F_IN + c0] : 0.f;
  float v1 = (c0 + 1 < F_IN) ? nf[(size_t)node * F_IN + c0 + 1] : 0.f;
  nfb[(size_t)node * 8 + li8] = (unsigned)f2bf(v0) | ((unsigned)f2bf(v1) << 16);
}

// ---------------- fused layer 0: aggregate bf16[16] + linear(11->128)+LN+ReLU -> bf16 x1 ----------------
__global__ __launch_bounds__(256) void k_l0(
    const unsigned* __restrict__ nfb, const int* __restrict__ csr,
    const int* __restrict__ offs, const int* __restrict__ deg,
    const float* __restrict__ W, const float* __restrict__ b,
    const float* __restrict__ g, const float* __restrict__ be,
    unsigned* __restrict__ xout, int n) {
  __shared__ float Ws[128 * F_IN];
  __shared__ float bs[128], gs[128], bes[128];
  __shared__ float xs[8][F_IN + 1];
  int t = threadIdx.x;
  for (int i = t; i < 128 * F_IN; i += 256) Ws[i] = W[i];
  if (t < 128) { bs[t] = b[t]; gs[t] = g[t]; bes[t] = be[t]; }
  int jg = t & 31, ng = t >> 5;            // 8 nodes per iter, 32-lane group per node
  int sub = (t >> 3) & 3, li8 = t & 7;     // 4 edges in flight, 8 lanes per 32B row
  for (int base = blockIdx.x * 8; base < n; base += gridDim.x * 8) {
    int node = base + ng;
    int o = offs[node], d = deg[node];
    float sx0 = 0.f, sy0 = 0.f, sx1 = 0.f, sy1 = 0.f;
    int e = 0;
    for (; e + 8 <= d; e += 8) {
      int i0 = csr[o + e + sub];
      int i1 = csr[o + e + 4 + sub];
      unsigned v0 = nfb[(size_t)i0 * 8 + li8];
      unsigned v1 = nfb[(size_t)i1 * 8 + li8];
      sx0 += bf_lo(v0); sy0 += bf_hi(v0);
      sx1 += bf_lo(v1); sy1 += bf_hi(v1);
    }
    for (; e < d; e += 4) {
      if (e + sub < d) {
        unsigned v = nfb[(size_t)csr[o + e + sub] * 8 + li8];
        sx0 += bf_lo(v); sy0 += bf_hi(v);
      }
    }
    float sx = sx0 + sx1, sy = sy0 + sy1;
    sx += __shfl_xor(sx, 8, 64);  sx += __shfl_xor(sx, 16, 64);
    sy += __shfl_xor(sy, 8, 64);  sy += __shfl_xor(sy, 16, 64);
    float rd = (d > 0) ? 1.f / (float)d : 1.f;
    __syncthreads();
    if (sub == 0) {
      int c0 = 2 * li8;
      if (c0 < F_IN) xs[ng][c0] = sx * rd;
      if (c0 + 1 < F_IN) xs[ng][c0 + 1] = sy * rd;
    }
    __syncthreads();
    // linear 11->128 + LN + ReLU
    float bm = (d > 0) ? 1.f : 0.f;
    float acc[4];
#pragma unroll
    for (int i = 0; i < 4; i++) acc[i] = bm * bs[4 * jg + i];
#pragma unroll
    for (int k = 0; k < F_IN; k++) {
      float xv = xs[ng][k];
#pragma unroll
      for (int i = 0; i < 4; i++) acc[i] += xv * Ws[(4 * jg + i) * F_IN + k];
    }
    float s1 = acc[0] + acc[1] + acc[2] + acc[3];
    float s2 = acc[0]*acc[0] + acc[1]*acc[1] + acc[2]*acc[2] + acc[3]*acc[3];
#pragma unroll
    for (int m = 1; m < 32; m <<= 1) {
      s1 += __shfl_xor(s1, m, 64);
      s2 += __shfl_xor(s2, m, 64);
    }
    float mu = s1 * (1.f / 128.f);
    float var = s2 * (1.f / 128.f) - mu * mu;
    float rs = rsqrtf(var + LN_EPS);
    float o4[4];
#pragma unroll
    for (int i = 0; i < 4; i++)
      o4[i] = fmaxf((acc[i] - mu) * rs * gs[4 * jg + i] + bes[4 * jg + i], 0.f);
    uint2 pk;
    pk.x = (unsigned)f2bf(o4[0]) | ((unsigned)f2bf(o4[1]) << 16);
    pk.y = (unsigned)f2bf(o4[2]) | ((unsigned)f2bf(o4[3]) << 16);
    ((uint2*)xout)[(size_t)node * 32 + jg] = pk;
  }
}

// ---------------- aggregate 128-dim bf16 (mean) -> bf16, wave/node, uint4 quarter-groups ----------------
__global__ __launch_bounds__(256) void k_agg128(
    const unsigned* __restrict__ X, const int* __restrict__ csr,
    const int* __restrict__ offs, const int* __restrict__ deg,
    unsigned* __restrict__ out, int n) {
  int t = threadIdx.x;
  int lane = t & 63;
  int sub = lane >> 4, li = lane & 15;     // 16 lanes x 16B cover one 256B row
  int node = blockIdx.x * 4 + (t >> 6);
  if (node >= n) return;
  int o = offs[node], d = deg[node];
  const uint4* X4 = (const uint4*)X;
  float a[8], b[8];
#pragma unroll
  for (int i = 0; i < 8; i++) { a[i] = 0.f; b[i] = 0.f; }
  int e = 0;
  for (; e + 16 <= d; e += 16) {
    int i0 = csr[o + e + sub];
    int i1 = csr[o + e + 4 + sub];
    int i2 = csr[o + e + 8 + sub];
    int i3 = csr[o + e + 12 + sub];
    uint4 v0 = X4[(size_t)i0 * 16 + li];
    uint4 v1 = X4[(size_t)i1 * 16 + li];
    uint4 v2 = X4[(size_t)i2 * 16 + li];
    uint4 v3 = X4[(size_t)i3 * 16 + li];
    ACC8(a, v0); ACC8(b, v1); ACC8(a, v2); ACC8(b, v3);
  }
  for (; e < d; e += 4) {
    if (e + sub < d) {
      uint4 v = X4[(size_t)csr[o + e + sub] * 16 + li];
      ACC8(a, v);
    }
  }
#pragma unroll
  for (int i = 0; i < 8; i++) {
    a[i] += b[i];
    a[i] += __shfl_xor(a[i], 16, 64);
    a[i] += __shfl_xor(a[i], 32, 64);
  }
  float rd = (d > 0) ? 1.f / (float)d : 1.f;
  if (sub == 0) {
    uint4 pk;
    pk.x = (unsigned)f2bf(a[0] * rd) | ((unsigned)f2bf(a[1] * rd) << 16);
    pk.y = (unsigned)f2bf(a[2] * rd) | ((unsigned)f2bf(a[3] * rd) << 16);
    pk.z = (unsigned)f2bf(a[4] * rd) | ((unsigned)f2bf(a[5] * rd) << 16);
    pk.w = (unsigned)f2bf(a[6] * rd) | ((unsigned)f2bf(a[7] * rd) << 16);
    ((uint4*)out)[(size_t)node * 16 + li] = pk;
  }
}

// ---------------- fused layer1+layer2 MFMA MLP ----------------
__global__ __launch_bounds__(256) void k_mlp(
    const unsigned* __restrict__ xa,
    const float* __restrict__ W1, const float* __restrict__ b1,
    const float* __restrict__ g1, const float* __restrict__ be1,
    const float* __restrict__ W2, const float* __restrict__ b2,
    const int* __restrict__ deg,
    unsigned* __restrict__ xt2, int n) {
  __shared__ short8 Wf1[32 * 64];
  __shared__ short8 Wf2[16 * 64];
  __shared__ unsigned bounce[4][1024];
  int t = threadIdx.x;
  int L = t & 63, w = t >> 6;
  for (int f = t; f < 2048; f += 256) {
    int tile = f >> 6, l = f & 63;
    int kt = tile >> 3, nt = tile & 7;
    const float* p = &W1[(nt * 16 + (l & 15)) * 128 + kt * 32 + (l >> 4) * 8];
    short8 v;
#pragma unroll
    for (int j = 0; j < 8; j++) v[j] = (short)f2bf(p[j]);
    Wf1[f] = v;
  }
  for (int f = t; f < 1024; f += 256) {
    int tile = f >> 6, l = f & 63;
    int kt = tile >> 2, nt = tile & 3;
    const float* p = &W2[(nt * 16 + (l & 15)) * 128 + kt * 32 + (l >> 4) * 8];
    short8 v;
#pragma unroll
    for (int j = 0; j < 8; j++) v[j] = (short)f2bf(p[j]);
    Wf2[f] = v;
  }
  int c = L & 15;
  float b1v[8], g1v[8], be1v[8], b2v[4];
#pragma unroll
  for (int nt = 0; nt < 8; nt++) {
    b1v[nt] = b1[nt * 16 + c];
    g1v[nt] = g1[nt * 16 + c];
    be1v[nt] = be1[nt * 16 + c];
  }
#pragma unroll
  for (int nt = 0; nt < 4; nt++) b2v[nt] = b2[nt * 16 + c];
  __syncthreads();

  int ntiles = n >> 4;
  unsigned* bw = bounce[w];
  int gg0 = (L >> 3) & 1;
  int odd = L & 1;
  for (int tile = blockIdx.x * 4 + w; tile < ntiles; tile += gridDim.x * 4) {
    int m0 = tile << 4;
    short8 a1[4];
    const char* xrow = (const char*)xa + (size_t)(m0 + c) * 256 + (L >> 4) * 16;
#pragma unroll
    for (int kt = 0; kt < 4; kt++) a1[kt] = *(const short8*)(xrow + kt * 64);
    f32x4 acc[8];
#pragma unroll
    for (int nt = 0; nt < 8; nt++) acc[nt] = (f32x4){0.f, 0.f, 0.f, 0.f};
#pragma unroll
    for (int kt = 0; kt < 4; kt++)
#pragma unroll
      for (int nt = 0; nt < 8; nt++)
        acc[nt] = __builtin_amdgcn_mfma_f32_16x16x32_bf16(
            a1[kt], Wf1[(kt * 8 + nt) * 64 + L], acc[nt], 0, 0, 0);
    int4 d4 = *(const int4*)&deg[m0 + (L >> 4) * 4];
    float mk[4];
    mk[0] = d4.x > 0 ? 1.f : 0.f; mk[1] = d4.y > 0 ? 1.f : 0.f;
    mk[2] = d4.z > 0 ? 1.f : 0.f; mk[3] = d4.w > 0 ? 1.f : 0.f;
#pragma unroll
    for (int nt = 0; nt < 8; nt++)
#pragma unroll
      for (int r = 0; r < 4; r++) acc[nt][r] += mk[r] * b1v[nt];
    float mu[4], rs[4];
#pragma unroll
    for (int r = 0; r < 4; r++) {
      float s1 = 0.f, s2 = 0.f;
#pragma unroll
      for (int nt = 0; nt < 8; nt++) { float v = acc[nt][r]; s1 += v; s2 += v * v; }
#pragma unroll
      for (int m = 1; m < 16; m <<= 1) {
        s1 += __shfl_xor(s1, m, 64);
        s2 += __shfl_xor(s2, m, 64);
      }
      float m_ = s1 * (1.f / 128.f);
      float var = s2 * (1.f / 128.f) - m_ * m_;
      mu[r] = m_;
      rs[r] = rsqrtf(var + LN_EPS);
    }
#pragma unroll
    for (int r = 0; r < 4; r++) {
      int rr = (L >> 4) * 4 + r;
#pragma unroll
      for (int p = 0; p < 4; p++) {
        float v0 = fmaxf((acc[2 * p][r] - mu[r]) * rs[r] * g1v[2 * p] + be1v[2 * p], 0.f);
        float v1 = fmaxf((acc[2 * p + 1][r] - mu[r]) * rs[r] * g1v[2 * p + 1] + be1v[2 * p + 1], 0.f);
        float u0 = __shfl_xor(v0, 1, 64);
        float u1 = __shfl_xor(v1, 1, 64);
        float w0 = odd ? u1 : v0;
        float w1 = odd ? v1 : u0;
        unsigned pk = (unsigned)f2bf(w0) | ((unsigned)f2bf(w1) << 16);
        int slot = rr + 16 * (gg0 + (odd ? 2 : 0));
        bw[p * 256 + slot * 4 + ((L & 6) >> 1)] = pk;
      }
    }
    short8 a2[4];
    const short8* br = (const short8*)bw;
#pragma unroll
    for (int kt = 0; kt < 4; kt++) a2[kt] = br[kt * 64 + L];
    f32x4 acc2[4];
#pragma unroll
    for (int nt = 0; nt < 4; nt++) acc2[nt] = (f32x4){0.f, 0.f, 0.f, 0.f};
#pragma unroll
    for (int kt = 0; kt < 4; kt++)
#pragma unroll
      for (int nt = 0; nt < 4; nt++)
        acc2[nt] = __builtin_amdgcn_mfma_f32_16x16x32_bf16(
            a2[kt], Wf2[(kt * 4 + nt) * 64 + L], acc2[nt], 0, 0, 0);
#pragma unroll
    for (int nt = 0; nt < 4; nt++)
#pragma unroll
      for (int r = 0; r < 4; r++) acc2[nt][r] += b2v[nt];
#pragma unroll
    for (int r = 0; r < 4; r++) {
      int rr = (L >> 4) * 4 + r;
#pragma unroll
      for (int p = 0; p < 2; p++) {
        float v0 = acc2[2 * p][r], v1 = acc2[2 * p + 1][r];
        float u0 = __shfl_xor(v0, 1, 64);
        float u1 = __shfl_xor(v1, 1, 64);
        float w0 = odd ? u1 : v0;
        float w1 = odd ? v1 : u0;
        unsigned pk = (unsigned)f2bf(w0) | ((unsigned)f2bf(w1) << 16);
        int j2 = 32 * p + (odd ? 16 : 0) + (L & 14);
        bw[rr * 32 + (j2 >> 1)] = pk;
      }
    }
    uint4* gout = (uint4*)((char*)xt2 + (size_t)m0 * 128);
    const uint4* brd = (const uint4*)bw;
    gout[L] = brd[L];
    gout[64 + L] = brd[64 + L];
  }
}

// ---------------- aggregate 64-dim bf16 (mean) + final LN, uint4 octet-groups ----------------
__global__ __launch_bounds__(256) void k_agg64_ln(
    const unsigned* __restrict__ X, const int* __restrict__ csr,
    const int* __restrict__ offs, const int* __restrict__ deg,
    const float* __restrict__ g, const float* __restrict__ be,
    float* __restrict__ out, int n) {
  int t = threadIdx.x;
  int lane = t & 31;                       // 32-lane group per node
  int sub = lane >> 3, li = lane & 7;      // 8 lanes x 16B cover one 128B row
  int node = blockIdx.x * 8 + (t >> 5);
  if (node >= n) return;
  int o = offs[node], d = deg[node];
  const uint4* X4 = (const uint4*)X;
  float a[8], b[8];
#pragma unroll
  for (int i = 0; i < 8; i++) { a[i] = 0.f; b[i] = 0.f; }
  int e = 0;
  for (; e + 16 <= d; e += 16) {
    int i0 = csr[o + e + sub];
    int i1 = csr[o + e + 4 + sub];
    int i2 = csr[o + e + 8 + sub];
    int i3 = csr[o + e + 12 + sub];
    uint4 v0 = X4[(size_t)i0 * 8 + li];
    uint4 v1 = X4[(size_t)i1 * 8 + li];
    uint4 v2 = X4[(size_t)i2 * 8 + li];
    uint4 v3 = X4[(size_t)i3 * 8 + li];
    ACC8(a, v0); ACC8(b, v1); ACC8(a, v2); ACC8(b, v3);
  }
  for (; e < d; e += 4) {
    if (e + sub < d) {
      uint4 v = X4[(size_t)csr[o + e + sub] * 8 + li];
      ACC8(a, v);
    }
  }
  float rd = (d > 0) ? 1.f / (float)d : 1.f;
  float v8[8];
  float s1 = 0.f, s2 = 0.f;
#pragma unroll
  for (int i = 0; i < 8; i++) {
    a[i] += b[i];
    a[i] += __shfl_xor(a[i], 8, 64);
    a[i] += __shfl_xor(a[i], 16, 64);
    v8[i] = a[i] * rd;
    s1 += v8[i];
    s2 += v8[i] * v8[i];
  }
#pragma unroll
  for (int m = 1; m < 8; m <<= 1) {        // reduce over the 8 li lanes
    s1 += __shfl_xor(s1, m, 64);
    s2 += __shfl_xor(s2, m, 64);
  }
  float mu = s1 * (1.f / 64.f);
  float var = s2 * (1.f / 64.f) - mu * mu;
  float rs = rsqrtf(var + LN_EPS);
  if (sub == 0) {
    float4 g0 = *(const float4*)&g[8 * li];
    float4 g1 = *(const float4*)&g[8 * li + 4];
    float4 e0 = *(const float4*)&be[8 * li];
    float4 e1 = *(const float4*)&be[8 * li + 4];
    float4 o0, o1;
    o0.x = (v8[0] - mu) * rs * g0.x + e0.x;
    o0.y = (v8[1] - mu) * rs * g0.y + e0.y;
    o0.z = (v8[2] - mu) * rs * g0.z + e0.z;
    o0.w = (v8[3] - mu) * rs * g0.w + e0.w;
    o1.x = (v8[4] - mu) * rs * g1.x + e1.x;
    o1.y = (v8[5] - mu) * rs * g1.y + e1.y;
    o1.z = (v8[6] - mu) * rs * g1.z + e1.z;
    o1.w = (v8[7] - mu) * rs * g1.w + e1.w;
    *(float4*)&out[(size_t)node * 64 + 8 * li] = o0;
    *(float4*)&out[(size_t)node * 64 + 8 * li + 4] = o1;
  }
}

extern "C" void kernel_launch(void* const* d_in, const int* in_sizes, int n_in,
                              void* d_out, int out_size, void* d_ws, size_t ws_size,
                              hipStream_t stream) {
  const float* nf  = (const float*)d_in[0];
  const int*   ei  = (const int*)d_in[1];
  const float* W0  = (const float*)d_in[2];
  const float* b0  = (const float*)d_in[3];
  const float* W1  = (const float*)d_in[4];
  const float* b1  = (const float*)d_in[5];
  const float* W2  = (const float*)d_in[6];
  const float* b2  = (const float*)d_in[7];
  const float* g0  = (const float*)d_in[8];
  const float* be0 = (const float*)d_in[9];
  const float* g1  = (const float*)d_in[10];
  const float* be1 = (const float*)d_in[11];
  const float* g2  = (const float*)d_in[12];
  const float* be2 = (const float*)d_in[13];
  float* out = (float*)d_out;

  int N = in_sizes[0] / F_IN;   // 100000
  int E = in_sizes[1] / 2;      // 1600000
  const int* src = ei;
  const int* tgt = ei + E;
  int NB = (N + 255) >> BKT_SHIFT;        // 391 buckets
  int NCH = (E + 4095) / 4096;            // 391 chunks

  char* w = (char*)d_ws;
  auto al = [](size_t x) { return (x + 255) & ~(size_t)255; };
  int* bcnt     = (int*)w;      w += al(512 * 4);
  int* bOffs    = (int*)w;      w += al(512 * 4);
  int* bcur     = (int*)w;      w += al(512 * 4);
  int* deg      = (int*)w;      w += al((size_t)N * 4);
  int* offs     = (int*)w;      w += al((size_t)N * 4);
  int* csr      = (int*)w;      w += al((size_t)E * 4);
  unsigned* tmp = (unsigned*)w; w += al((size_t)E * 4);
  unsigned* nfb = (unsigned*)w; w += al((size_t)N * 32);        // bf16 [N][16]
  unsigned* x1  = (unsigned*)w; w += al((size_t)N * 256);       // bf16 [N][128]
  unsigned* axg = (unsigned*)w; w += al((size_t)N * 256);       // bf16 [N][128]
  unsigned* xt2 = (unsigned*)w; w += al((size_t)N * 128);       // bf16 [N][64]

  hipMemsetAsync(bcnt, 0, 512 * 4, stream);

  // CSR build (bucketed counting sort; also produces deg/offs)
  k_bhist<<<256, 256, 0, stream>>>(tgt, bcnt, E, NB);
  k_bscan<<<1, 512, 0, stream>>>(bcnt, bOffs, bcur, NB);
  k_bin<<<NCH, 256, 0, stream>>>(src, tgt, bcur, tmp, E, NB);
  k_bucket<<<NB, 256, 0, stream>>>(tmp, bOffs, bcnt, deg, offs, csr, N);

  // input features -> padded bf16 [N][16]
  k_cvt<<<(N * 8 + 255) / 256, 256, 0, stream>>>(nf, nfb, N);

  // layer 0 fused: aggregate + linear+LN+ReLU -> bf16 x1
  k_l0<<<(N + 7) / 8, 256, 0, stream>>>(nfb, csr, offs, deg, W0, b0, g0, be0, x1, N);

  // layer 1 aggregation: bf16 x1 -> bf16 aggregated (fp32 accumulate)
  k_agg128<<<(N + 3) / 4, 256, 0, stream>>>(x1, csr, offs, deg, axg, N);

  // fused layer1 linear+LN+ReLU + layer2 linear (MFMA) -> bf16 xt2
  k_mlp<<<512, 256, 0, stream>>>(axg, W1, b1, g1, be1, W2, b2, deg, xt2, N);

  // layer 2 aggregation + final LN -> out
  k_agg64_ln<<<(N + 7) / 8, 256, 0, stream>>>(xt2, csr, offs, deg, g2, be2, out, N);
}